// Round 8
// baseline (4852.205 us; speedup 1.0000x reference)
//
#include <hip/hip_runtime.h>
#include <math.h>

#define BB 8
#define NN 2048
#define PP 64
#define KK 32
#define DD 384
#define DEPTH 12
#define DI 768
#define DS 16
#define DCONV 4
#define DTR 24
#define NC 40
#define LL 128  // 2*PP
#define XROW (DTR + 2 * DS)  // 56
#define NR (BB * LL)         // 1024
#define GRID_G 512           // persistent-kernel grid (2 blocks/CU on 256 CUs)

using bf16x8 = __attribute__((ext_vector_type(8))) short;
using floatx4 = __attribute__((ext_vector_type(4))) float;

// ---------------------------------------------------------------- helpers
__device__ __forceinline__ float gelu_exact(float x) {
    return 0.5f * x * (1.0f + erff(x * 0.70710678118654752440f));
}
__device__ __forceinline__ float siluf(float x) {
    return x / (1.0f + expf(-x));
}
__device__ __forceinline__ unsigned short f2bf(float f) {
    unsigned u = __float_as_uint(f);
    u += 0x7fffu + ((u >> 16) & 1u);   // round-to-nearest-even
    return (unsigned short)(u >> 16);
}
__device__ __forceinline__ float bf2f(short s) {
    return __uint_as_float(((unsigned)(unsigned short)s) << 16);
}
__device__ __forceinline__ unsigned spread_bits(unsigned v) {
    v &= 1023u;
    v = (v | (v << 16)) & 50331903u;
    v = (v | (v << 8)) & 50393103u;
    v = (v | (v << 4)) & 51130563u;
    v = (v | (v << 2)) & 153391689u;
    return v;
}

// manual grid barrier: monotonic counter, device-scope atomics, per-block thread-0 fence.
// All GRID_G blocks are co-resident (launch_bounds(256,2), LDS 17.9KB) -> no deadlock.
__device__ __forceinline__ void grid_sync(int* bar, int target) {
    __syncthreads();
    if (threadIdx.x == 0) {
        __threadfence();   // release: make this block's writes visible device-wide
        __hip_atomic_fetch_add(bar, 1, __ATOMIC_ACQ_REL, __HIP_MEMORY_SCOPE_AGENT);
        while (__hip_atomic_load(bar, __ATOMIC_ACQUIRE, __HIP_MEMORY_SCOPE_AGENT) < target)
            __builtin_amdgcn_s_sleep(2);
        __threadfence();   // acquire: invalidate this block's caches
    }
    __syncthreads();
}

// ---------------------------------------------------------------- one-shot weight conversions (float4-vectorized)
__global__ void k_cvt(const float* __restrict__ in_w, const float* __restrict__ out_w,
                      const float* __restrict__ pe_w3, const float* __restrict__ xp,
                      const float* __restrict__ w2,
                      unsigned short* __restrict__ inwbf, unsigned short* __restrict__ owbf,
                      unsigned short* __restrict__ w3bf, unsigned short* __restrict__ xpbf,
                      unsigned short* __restrict__ w2bf)
{
    int idx = (blockIdx.x * 256 + threadIdx.x) * 4;
    const int n1 = DEPTH * 2 * DI * DD;
    const int n2 = DEPTH * DD * DI;
    const int n3 = DD * 128;
    const int n4 = DEPTH * 64 * DI;
    const int n5 = 128 * 64;
    if (idx < n1) {
        float4 v = *(const float4*)(in_w + idx);
        ushort4 o; o.x = f2bf(v.x); o.y = f2bf(v.y); o.z = f2bf(v.z); o.w = f2bf(v.w);
        *(ushort4*)(inwbf + idx) = o;
        return;
    }
    idx -= n1;
    if (idx < n2) {
        float4 v = *(const float4*)(out_w + idx);
        ushort4 o; o.x = f2bf(v.x); o.y = f2bf(v.y); o.z = f2bf(v.z); o.w = f2bf(v.w);
        *(ushort4*)(owbf + idx) = o;
        return;
    }
    idx -= n2;
    if (idx < n3) {
        float4 v = *(const float4*)(pe_w3 + idx);
        ushort4 o; o.x = f2bf(v.x); o.y = f2bf(v.y); o.z = f2bf(v.z); o.w = f2bf(v.w);
        *(ushort4*)(w3bf + idx) = o;
        return;
    }
    idx -= n3;
    if (idx < n4) {
        int i = idx / (64 * DI);
        int rem = idx - i * 64 * DI;
        int n = rem / DI, k = rem % DI;   // k multiple of 4, same row for all 4
        ushort4 o;
        if (n < XROW) {
            float4 v = *(const float4*)(xp + (size_t)i * XROW * DI + (size_t)n * DI + k);
            o.x = f2bf(v.x); o.y = f2bf(v.y); o.z = f2bf(v.z); o.w = f2bf(v.w);
        } else {
            o.x = o.y = o.z = o.w = 0;
        }
        *(ushort4*)(xpbf + (size_t)i * 64 * DI + (size_t)n * DI + k) = o;
        return;
    }
    idx -= n4;
    if (idx < n5) {
        float4 v = *(const float4*)(w2 + idx);
        ushort4 o; o.x = f2bf(v.x); o.y = f2bf(v.y); o.z = f2bf(v.z); o.w = f2bf(v.w);
        *(ushort4*)(w2bf + idx) = o;
    }
}

// ---------------------------------------------------------------- KNN (radix-select) + patch-embed MLP fused: one block per (b,p)
__global__ __launch_bounds__(256) void k_patch(
    const float* __restrict__ data,
    const float* __restrict__ w1, const float* __restrict__ b1,
    const float* __restrict__ g1, const float* __restrict__ be1,
    const unsigned short* __restrict__ w2bf, const float* __restrict__ b2,
    const float* __restrict__ g2, const float* __restrict__ be2,
    const unsigned short* __restrict__ w3bf, const float* __restrict__ b3,
    const float* __restrict__ g3, const float* __restrict__ be3,
    float* __restrict__ tokens, float* __restrict__ centers)
{
    const int bp = blockIdx.x;
    const int b = bp >> 6, p = bp & 63;
    const int tid = threadIdx.x;
    const float* X = data + (size_t)b * NN * 3;
    const float inv_den = 0.99999500003749968752f; // 1/sqrt(1+1e-5)

    __shared__ int hist[4][4][256];   // [round][wave][bin] -> zeroed once
    __shared__ int klist[KK];
    __shared__ int eqlist[256];
    __shared__ int s_kth, s_byte, s_cnt, s_eqcnt;
    __shared__ float nxs[KK * 3];
    __shared__ short h1b[KK][72];
    __shared__ short h2b[KK][136];

    const float cx = X[p * 32 * 3 + 0];
    const float cy = X[p * 32 * 3 + 1];
    const float cz = X[p * 32 * 3 + 2];
    if (tid == 0) {
        centers[(b * PP + p) * 3 + 0] = cx;
        centers[(b * PP + p) * 3 + 1] = cy;
        centers[(b * PP + p) * 3 + 2] = cz;
        s_kth = KK; s_cnt = 0; s_eqcnt = 0;
    }
    for (int i = tid; i < 4 * 4 * 256; i += 256) ((int*)hist)[i] = 0;

    const int wave = tid >> 6, lane = tid & 63;

    // ---- KNN phase: radix-select the 32 smallest d2 keys
    {
        unsigned key[8];
#pragma unroll
        for (int q = 0; q < 8; q++) {
            int i = tid + 256 * q;
            float dx = cx - X[i * 3 + 0];
            float dy = cy - X[i * 3 + 1];
            float dz = cz - X[i * 3 + 2];
            float d2 = dx * dx + dy * dy + dz * dz;
            key[q] = __float_as_uint(d2);
        }
        __syncthreads();
        unsigned prefix = 0;
        for (int rnd = 3; rnd >= 0; rnd--) {
            const int sh = rnd * 8;
            const int rslot = 3 - rnd;
            const unsigned pmask = (rnd == 3) ? 0u : (0xFFFFFFFFu << (8 * (rnd + 1)));
#pragma unroll
            for (int q = 0; q < 8; q++)
                if ((key[q] & pmask) == prefix)
                    atomicAdd(&hist[rslot][wave][(key[q] >> sh) & 255], 1);
            __syncthreads();
            if (wave == 0) {
                int c[4], tot = 0;
#pragma unroll
                for (int j = 0; j < 4; j++) {
                    int s4 = 0;
#pragma unroll
                    for (int w = 0; w < 4; w++) s4 += hist[rslot][w][lane * 4 + j];
                    c[j] = s4; tot += s4;
                }
                int inc = tot;
#pragma unroll
                for (int off = 1; off < 64; off <<= 1) {
                    int u = __shfl_up(inc, off);
                    if (lane >= off) inc += u;
                }
                int exc = inc - tot;
                int kth = s_kth;
                bool has = (exc < kth) && (exc + tot >= kth);
                unsigned long long bal = __ballot(has);
                int src = __ffsll(bal) - 1;
                if (lane == src) {
                    int rem = kth - exc;
                    int j = 0, cum = 0;
                    while (cum + c[j] < rem) { cum += c[j]; j++; }
                    s_byte = lane * 4 + j;
                    s_kth = rem - cum;
                }
            }
            __syncthreads();
            prefix |= ((unsigned)s_byte) << sh;
        }
        const unsigned kstar = prefix;
        const int need = s_kth;
#pragma unroll
        for (int q = 0; q < 8; q++) {
            int i = tid + 256 * q;
            if (key[q] < kstar) {
                int pos = atomicAdd(&s_cnt, 1);
                klist[pos] = i;
            } else if (key[q] == kstar) {
                int pos = atomicAdd(&s_eqcnt, 1);
                if (pos < 256) eqlist[pos] = i;
            }
        }
        __syncthreads();
        if (tid == 0) {
            int base = s_cnt;
            int ne = s_eqcnt < 256 ? s_eqcnt : 256;
            for (int k = 0; k < need; k++) {
                int best = 0x7fffffff, bi = 0;
                for (int j = 0; j < ne; j++)
                    if (eqlist[j] < best) { best = eqlist[j]; bi = j; }
                klist[base + k] = best;
                eqlist[bi] = 0x7fffffff;
            }
        }
        __syncthreads();
    }

    // ---- patch-embed MLP phase
    if (tid < KK) {
        int q = klist[tid];
        nxs[tid * 3 + 0] = X[q * 3 + 0] - cx;
        nxs[tid * 3 + 1] = X[q * 3 + 1] - cy;
        nxs[tid * 3 + 2] = X[q * 3 + 2] - cz;
    }
    __syncthreads();

    for (int e = tid; e < KK * 64; e += 256) {
        int j = e >> 6, c = e & 63;
        float v = nxs[j * 3 + 0] * w1[c * 3 + 0] + nxs[j * 3 + 1] * w1[c * 3 + 1] +
                  nxs[j * 3 + 2] * w1[c * 3 + 2] + b1[c];
        v = v * (g1[c] * inv_den) + be1[c];
        h1b[j][c] = (short)f2bf(gelu_exact(v));
    }
    __syncthreads();

    const int quad = lane >> 4, r = lane & 15;

    // layer 2: 64 -> 128 via MFMA
    {
        floatx4 acc2[2][2] = {};
#pragma unroll
        for (int ks = 0; ks < 2; ks++) {
            const int k0 = ks * 32;
            bf16x8 af[2], bfv[2];
#pragma unroll
            for (int mi = 0; mi < 2; mi++)
                af[mi] = *(const bf16x8*)&h1b[mi * 16 + r][quad * 8 + k0];
#pragma unroll
            for (int jj = 0; jj < 2; jj++) {
                int n = wave * 32 + jj * 16 + r;
                bfv[jj] = *(const bf16x8*)(w2bf + (size_t)n * 64 + quad * 8 + k0);
            }
#pragma unroll
            for (int mi = 0; mi < 2; mi++)
#pragma unroll
                for (int jj = 0; jj < 2; jj++)
                    acc2[mi][jj] = __builtin_amdgcn_mfma_f32_16x16x32_bf16(af[mi], bfv[jj], acc2[mi][jj], 0, 0, 0);
        }
#pragma unroll
        for (int jj = 0; jj < 2; jj++) {
            int col = wave * 32 + jj * 16 + r;
            float sc = g2[col] * inv_den;
            float bb = b2[col] * sc + be2[col];
#pragma unroll
            for (int mi = 0; mi < 2; mi++)
#pragma unroll
                for (int r2 = 0; r2 < 4; r2++) {
                    int row = mi * 16 + quad * 4 + r2;
                    h2b[row][col] = (short)f2bf(gelu_exact(acc2[mi][jj][r2] * sc + bb));
                }
        }
    }
    __syncthreads();

    // layer 3: 128 -> 384 via MFMA + max over K
    floatx4 acc3[2][6] = {};
#pragma unroll
    for (int ks = 0; ks < 4; ks++) {
        const int k0 = ks * 32;
        bf16x8 af[2];
        af[0] = *(const bf16x8*)&h2b[r][quad * 8 + k0];
        af[1] = *(const bf16x8*)&h2b[16 + r][quad * 8 + k0];
        bf16x8 bfv[6];
#pragma unroll
        for (int nj = 0; nj < 6; nj++) {
            int n = wave * 96 + nj * 16 + r;
            bfv[nj] = *(const bf16x8*)(w3bf + (size_t)n * 128 + quad * 8 + k0);
        }
#pragma unroll
        for (int mi = 0; mi < 2; mi++)
#pragma unroll
            for (int nj = 0; nj < 6; nj++)
                acc3[mi][nj] = __builtin_amdgcn_mfma_f32_16x16x32_bf16(af[mi], bfv[nj], acc3[mi][nj], 0, 0, 0);
    }
#pragma unroll
    for (int nj = 0; nj < 6; nj++) {
        int col = wave * 96 + nj * 16 + r;
        float sc = g3[col] * inv_den;
        float offc = b3[col] * sc + be3[col];
        float m = -3.4e38f;
#pragma unroll
        for (int mi = 0; mi < 2; mi++)
#pragma unroll
            for (int r2 = 0; r2 < 4; r2++)
                m = fmaxf(m, acc3[mi][nj][r2] * sc + offc);
        m = fmaxf(m, __shfl_xor(m, 16));
        m = fmaxf(m, __shfl_xor(m, 32));
        if (quad == 0) tokens[(size_t)bp * DD + col] = m;
    }
}

// ---------------------------------------------------------------- SFC orders + build token sequence fused; zero barrier counter.
__global__ __launch_bounds__(256) void k_sfc_build(
    const float* __restrict__ centers, const float* __restrict__ tokens,
    const float* __restrict__ hs, const float* __restrict__ hb,
    const float* __restrict__ ts2, const float* __restrict__ tb2,
    const float* __restrict__ pos, float* __restrict__ tout,
    int* __restrict__ bar)
{
    const int b = blockIdx.y, part = blockIdx.x;
    const int tid = threadIdx.x;

    if (b == 0 && part == 0 && tid == 0) *bar = 0;   // reset grid-barrier counter each launch

    __shared__ float csh[PP][3];
    __shared__ float slo[3], shi[3];
    __shared__ unsigned khs[PP], kts[PP];
    __shared__ int oh[PP], ot[PP];

    if (tid < PP) {
        csh[tid][0] = centers[(b * PP + tid) * 3 + 0];
        csh[tid][1] = centers[(b * PP + tid) * 3 + 1];
        csh[tid][2] = centers[(b * PP + tid) * 3 + 2];
    }
    __syncthreads();
    if (tid == 0) {
        for (int k = 0; k < 3; k++) {
            float lo = csh[0][k], hi = csh[0][k];
            for (int j = 1; j < PP; j++) { lo = fminf(lo, csh[j][k]); hi = fmaxf(hi, csh[j][k]); }
            slo[k] = lo; shi[k] = hi;
        }
    }
    __syncthreads();
    if (tid < PP) {
        int q[3];
        for (int k = 0; k < 3; k++) {
            float t = (csh[tid][k] - slo[k]) / (shi[k] - slo[k] + 1e-6f) * 1023.0f;
            int qi = (int)t;
            qi = qi < 0 ? 0 : (qi > 1023 ? 1023 : qi);
            q[k] = qi;
        }
        khs[tid] = spread_bits((unsigned)q[0]) | (spread_bits((unsigned)q[1]) << 1) |
                   (spread_bits((unsigned)q[2]) << 2);
        kts[tid] = spread_bits((unsigned)q[2]) | (spread_bits((unsigned)q[1]) << 1) |
                   (spread_bits((unsigned)q[0]) << 2);
    }
    __syncthreads();
    if (tid < PP) {
        unsigned kh = khs[tid], kt = kts[tid];
        int rh = 0, rt = 0;
        for (int j = 0; j < PP; j++) {
            unsigned a = khs[j];
            rh += (a < kh) || (a == kh && j < tid);
            unsigned c = kts[j];
            rt += (c < kt) || (c == kt && j < tid);
        }
        oh[rh] = tid;
        ot[rt] = tid;
    }
    __syncthreads();

    const int base = part * (LL * DD / 24);  // 2048-element slice
    for (int e = tid; e < LL * DD / 24; e += 256) {
        int idx = base + e;
        int d = idx % DD;
        int l = idx / DD;
        float v;
        if (l < PP) {
            int src = oh[l];
            v = tokens[((size_t)b * PP + src) * DD + d] * hs[d] + hb[d] + pos[l * DD + d];
        } else {
            int l2 = l - PP;
            int src = ot[l2];
            v = tokens[((size_t)b * PP + src) * DD + d] * ts2[d] + tb2[d] + pos[l2 * DD + d];
        }
        tout[(size_t)b * LL * DD + idx] = v;
    }
}

// ---------------------------------------------------------------- persistent kernel: all 12 layers, manual grid barrier.
// Grid GRID_G x 256, launch_bounds(256,2): all blocks co-resident (LDS 17.9KB, 2/CU).
// Phases per layer (r4/r5-verified bodies, gridDim-stride virtual tiles):
//  A: LN -> tbf + zero xdbl | B: xz GEMM 32-col tiles + conv/SiLU + xdbl atomics |
//  C: selective scan (2 units/block) | D: out-proj split-K2 atomic residual
__global__ __launch_bounds__(256, 2) void k_layers(
    float* __restrict__ t, float* __restrict__ xdbl,
    unsigned short* __restrict__ tbf, unsigned short* __restrict__ xcbf,
    unsigned short* __restrict__ zsbf, unsigned short* __restrict__ ybf,
    const unsigned short* __restrict__ inwbf_a, const unsigned short* __restrict__ owbf_a,
    const unsigned short* __restrict__ xpbf_a,
    const float* __restrict__ lng_a, const float* __restrict__ lnb_a,
    const float* __restrict__ cw_a, const float* __restrict__ cb_a,
    const float* __restrict__ dtw_a, const float* __restrict__ dtb_a,
    const float* __restrict__ Al_a, const float* __restrict__ Dp_a,
    int* __restrict__ bar)
{
    const int bid = blockIdx.x;
    const int tid = threadIdx.x;
    const int G = GRID_G;
    int gen = 0;

    __shared__ short ct[128][40];                 // phase B, 10 KB
    __shared__ float sdel[2][LL], sdus[2][LL], sus[2][LL], szs[2][LL];  // phase C
    __shared__ float negA[2][DS];
    __shared__ float ApL[2][DS][9], HlL[2][DS][9], hst[2][DS][9];

    for (int layer = 0; layer < DEPTH; layer++) {
        const unsigned short* inwbf = inwbf_a + (size_t)layer * 2 * DI * DD;
        const unsigned short* owbf  = owbf_a + (size_t)layer * DD * DI;
        const unsigned short* xpbf  = xpbf_a + (size_t)layer * 64 * DI;
        const float* ln_g = lng_a + layer * DD;
        const float* ln_b = lnb_a + layer * DD;
        const float* cw   = cw_a + (size_t)layer * DI * DCONV;
        const float* cb   = cb_a + (size_t)layer * DI;
        const float* dtw  = dtw_a + (size_t)layer * DI * DTR;
        const float* dtb  = dtb_a + (size_t)layer * DI;
        const float* Al   = Al_a + (size_t)layer * DI * DS;
        const float* Dp   = Dp_a + (size_t)layer * DI;

        // ---------------- Phase A: LN -> tbf, zero xdbl
        for (int vb = bid; vb < NR / 4; vb += G) {
            const int wid = tid >> 6, lane = tid & 63;
            const int row = vb * 4 + wid;
            const size_t base = (size_t)row * DD;
            float v[6];
            float s = 0.f, q = 0.f;
#pragma unroll
            for (int j = 0; j < 6; j++) {
                v[j] = t[base + lane + 64 * j];
                s += v[j]; q += v[j] * v[j];
            }
#pragma unroll
            for (int off = 32; off; off >>= 1) { s += __shfl_xor(s, off); q += __shfl_xor(q, off); }
            float mean = s * (1.0f / DD);
            float var = q * (1.0f / DD) - mean * mean;
            float inv = 1.0f / sqrtf(var + 1e-5f);
#pragma unroll
            for (int j = 0; j < 6; j++) {
                int i = lane + 64 * j;
                tbf[base + i] = f2bf((v[j] - mean) * inv * ln_g[i] + ln_b[i]);
            }
        }
        for (int gi = bid * 256 + tid; gi < NR * XROW; gi += G * 256) xdbl[gi] = 0.f;
        grid_sync(bar, ++gen * G);

        // ---------------- Phase B: xz GEMM (128 x 32-col tiles) + conv/SiLU + xdbl partial
        for (int vt = bid; vt < 48 * BB; vt += G) {
            const int b = vt / 48;
            const int tx = vt - b * 48;
            const int wave = tid >> 6, lane = tid & 63;
            const int quad = lane >> 4, r = lane & 15;
            const int n0 = tx * 32;
            const int m0 = b * 128 + wave * 32;

            floatx4 acc[2][2] = {};
            const unsigned short* Ab = tbf + (size_t)(m0 + r) * DD + quad * 8;
            const unsigned short* Bb = inwbf + (size_t)(n0 + r) * DD + quad * 8;
            for (int k0 = 0; k0 < DD; k0 += 32) {
                bf16x8 af[2], bfv[2];
#pragma unroll
                for (int i = 0; i < 2; i++)
                    af[i] = *(const bf16x8*)(Ab + (size_t)(i * 16) * DD + k0);
#pragma unroll
                for (int j = 0; j < 2; j++)
                    bfv[j] = *(const bf16x8*)(Bb + (size_t)(j * 16) * DD + k0);
#pragma unroll
                for (int i = 0; i < 2; i++)
#pragma unroll
                    for (int j = 0; j < 2; j++)
                        acc[i][j] = __builtin_amdgcn_mfma_f32_16x16x32_bf16(af[i], bfv[j], acc[i][j], 0, 0, 0);
            }

#pragma unroll
            for (int i = 0; i < 2; i++)
#pragma unroll
                for (int r2 = 0; r2 < 4; r2++) {
                    short* cp = &ct[wave * 32 + i * 16 + quad * 4 + r2][r];
#pragma unroll
                    for (int j = 0; j < 2; j++)
                        cp[j * 16] = (short)f2bf(acc[i][j][r2]);
                }
            __syncthreads();

            const int l0 = (tid >> 2) * 2;      // 2 rows per thread
            const int c0 = (tid & 3) * 8;       // 8 cols per thread
            if (n0 < DI) {
                float cwv[8][4], cbv[8];
#pragma unroll
                for (int q = 0; q < 8; q++) {
                    *(float4*)cwv[q] = *(const float4*)(cw + (size_t)(n0 + c0 + q) * 4);
                    cbv[q] = cb[n0 + c0 + q];
                }
                unsigned short ov[2][8];
#pragma unroll
                for (int dl = 0; dl < 2; dl++) {
                    const int l = l0 + dl;
                    float u[8];
#pragma unroll
                    for (int q = 0; q < 8; q++) u[q] = cbv[q];
#pragma unroll
                    for (int j = 0; j < DCONV; j++) {
                        int lt = l - (DCONV - 1) + j;
                        if (lt >= 0) {
                            bf16x8 x = *(const bf16x8*)&ct[lt][c0];
#pragma unroll
                            for (int q = 0; q < 8; q++) u[q] += bf2f(x[q]) * cwv[q][j];
                        }
                    }
#pragma unroll
                    for (int q = 0; q < 8; q++) ov[dl][q] = f2bf(siluf(u[q]));
                }
                __syncthreads();   // all pre-conv reads done
#pragma unroll
                for (int dl = 0; dl < 2; dl++) {
                    const int l = l0 + dl;
                    *(bf16x8*)&ct[l][c0] = *(bf16x8*)ov[dl];
                    *(bf16x8*)(xcbf + (size_t)(b * LL + l) * DI + n0 + c0) = *(bf16x8*)ov[dl];
                }
                __syncthreads();

                // fused xdbl partial: K = 32, 4 waves x 32 rows, 1 k-step
                floatx4 acc2[2][4] = {};
                {
                    bf16x8 af2[2], bfv2[4];
#pragma unroll
                    for (int i = 0; i < 2; i++)
                        af2[i] = *(const bf16x8*)&ct[wave * 32 + i * 16 + r][quad * 8];
#pragma unroll
                    for (int nj = 0; nj < 4; nj++)
                        bfv2[nj] = *(const bf16x8*)(xpbf + (size_t)(nj * 16 + r) * DI + n0 + quad * 8);
#pragma unroll
                    for (int i = 0; i < 2; i++)
#pragma unroll
                        for (int nj = 0; nj < 4; nj++)
                            acc2[i][nj] = __builtin_amdgcn_mfma_f32_16x16x32_bf16(af2[i], bfv2[nj], acc2[i][nj], 0, 0, 0);
                }
#pragma unroll
                for (int i = 0; i < 2; i++)
#pragma unroll
                    for (int nj = 0; nj < 4; nj++) {
                        int col = nj * 16 + r;
                        if (col < XROW) {
#pragma unroll
                            for (int r2 = 0; r2 < 4; r2++) {
                                int row = b * LL + wave * 32 + i * 16 + quad * 4 + r2;
                                unsafeAtomicAdd(&xdbl[(size_t)row * XROW + col], acc2[i][nj][r2]);
                            }
                        }
                    }
            } else {
                const int nz = n0 - DI;
#pragma unroll
                for (int dl = 0; dl < 2; dl++) {
                    const int l = l0 + dl;
                    bf16x8 x = *(const bf16x8*)&ct[l][c0];
                    unsigned short o[8];
#pragma unroll
                    for (int q = 0; q < 8; q++) o[q] = f2bf(siluf(bf2f(x[q])));
                    *(bf16x8*)(zsbf + (size_t)(b * LL + l) * DI + nz + c0) = *(bf16x8*)o;
                }
            }
            __syncthreads();   // protect ct reuse next trip
        }
        grid_sync(bar, ++gen * G);

        // ---------------- Phase C: selective scan, 2 units (128 thr) per block
        {
            const int unit = tid >> 7, ut = tid & 127;
            for (int vu = bid * 2 + unit; vu < BB * DI; vu += G * 2) {
                const int b = vu / DI;
                const int d = vu - b * DI;

                {
                    const int tk = ut;
                    const size_t row = (size_t)b * LL + tk;
                    const float* xd = xdbl + row * XROW;
                    const float* w = dtw + d * DTR;
                    float acc = dtb[d];
#pragma unroll
                    for (int k = 0; k < DTR; k += 4) {
                        float4 xv = *(const float4*)(xd + k);
                        float4 wv = *(const float4*)(w + k);
                        acc += xv.x * wv.x + xv.y * wv.y + xv.z * wv.z + xv.w * wv.w;
                    }
                    float delta = fmaxf(acc, 0.f) + log1pf(__expf(-fabsf(acc)));  // softplus
                    float u = bf2f((short)xcbf[row * DI + d]);
                    sdel[unit][tk] = delta;
                    sdus[unit][tk] = delta * u;
                    sus[unit][tk] = u;
                    szs[unit][tk] = bf2f((short)zsbf[row * DI + d]);
                }
                if (ut < DS) negA[unit][ut] = -__expf(Al[d * DS + ut]);
                __syncthreads();

                const int s = ut & 15;
                const int c = ut >> 4;           // chunk 0..7
                const float* xB = xdbl + ((size_t)b * LL + c * 16) * XROW + DTR + s;

                float a_r[16], duB_r[16], C_r[16];
                {
                    float h = 0.f, Ap = 1.f;
                    const float na = negA[unit][s];
#pragma unroll
                    for (int q = 0; q < 16; q++) {
                        int tk = c * 16 + q;
                        float a = __expf(sdel[unit][tk] * na);
                        float Bv = xB[(size_t)q * XROW];
                        float Cv = xB[(size_t)q * XROW + DS];
                        a_r[q] = a;
                        duB_r[q] = sdus[unit][tk] * Bv;
                        C_r[q] = Cv;
                        h = h * a + duB_r[q];
                        Ap *= a;
                    }
                    ApL[unit][s][c] = Ap;
                    HlL[unit][s][c] = h;
                }
                __syncthreads();
                if (ut < DS) {
                    float hs = 0.f;
#pragma unroll
                    for (int cc = 0; cc < 8; cc++) {
                        hst[unit][ut][cc] = hs;
                        hs = ApL[unit][ut][cc] * hs + HlL[unit][ut][cc];
                    }
                }
                __syncthreads();

                {
                    const float Dd = Dp[d];
                    float h = hst[unit][s][c];
                    unsigned short* yc = ybf + ((size_t)b * LL + c * 16) * DI + d;
#pragma unroll
                    for (int q = 0; q < 16; q++) {
                        h = h * a_r[q] + duB_r[q];
                        float p = h * C_r[q];
                        p += __shfl_xor(p, 1, 16);
                        p += __shfl_xor(p, 2, 16);
                        p += __shfl_xor(p, 4, 16);
                        p += __shfl_xor(p, 8, 16);
                        if (s == 0) {
                            int tk = c * 16 + q;
                            yc[(size_t)q * DI] = f2bf((p + Dd * sus[unit][tk]) * szs[unit][tk]);
                        }
                    }
                }
                __syncthreads();   // protect scan LDS reuse next trip
            }
        }
        grid_sync(bar, ++gen * G);

        // ---------------- Phase D: out-proj split-K2, atomic residual on t
        for (int vt = bid; vt < 6 * 32 * 2; vt += G) {
            const int bx = vt % 6;
            const int rest = vt / 6;
            const int by = rest & 31;
            const int bz = rest >> 5;
            const int wave = tid >> 6, lane = tid & 63;
            const int quad = lane >> 4, r = lane & 15;
            const int wr2 = wave >> 1, wc = wave & 1;
            const int n0 = bx * 64 + wc * 32;
            const int m0 = by * 32 + wr2 * 16;
            const int kb = bz * (DI / 2);

            floatx4 acc[2] = {};
            const unsigned short* Ab = ybf + (size_t)(m0 + r) * DI + kb + quad * 8;
            const unsigned short* Bb = owbf + (size_t)(n0 + r) * DI + kb + quad * 8;
            for (int k0 = 0; k0 < DI / 2; k0 += 32) {
                bf16x8 af = *(const bf16x8*)(Ab + k0);
                bf16x8 b0 = *(const bf16x8*)(Bb + k0);
                bf16x8 b1 = *(const bf16x8*)(Bb + (size_t)16 * DI + k0);
                acc[0] = __builtin_amdgcn_mfma_f32_16x16x32_bf16(af, b0, acc[0], 0, 0, 0);
                acc[1] = __builtin_amdgcn_mfma_f32_16x16x32_bf16(af, b1, acc[1], 0, 0, 0);
            }
#pragma unroll
            for (int j = 0; j < 2; j++) {
                int col = n0 + j * 16 + r;
#pragma unroll
                for (int r2 = 0; r2 < 4; r2++) {
                    int row = m0 + quad * 4 + r2;
                    unsafeAtomicAdd(t + (size_t)row * DD + col, acc[j][r2]);
                }
            }
        }
        grid_sync(bar, ++gen * G);
    }
}

// ---------------------------------------------------------------- final LN + partial mean-pool: grid (8 chunks, 8 batches)
__global__ __launch_bounds__(256) void k_lnpool(const float* __restrict__ t,
                                                const float* __restrict__ ng,
                                                const float* __restrict__ nb,
                                                float* __restrict__ pparts)  // [BB][8][DD]
{
    const int b = blockIdx.y, chunk = blockIdx.x;
    const int tid = threadIdx.x;
    const int wave = tid >> 6, lane = tid & 63;
    __shared__ float pw[4][DD];

    for (int c = lane; c < DD; c += 64) pw[wave][c] = 0.f;
    __syncthreads();

    for (int rr = 0; rr < 4; rr++) {
        const int row = b * LL + chunk * 16 + wave * 4 + rr;
        const float* xr = t + (size_t)row * DD;
        float v[6];
        float s = 0.f, q = 0.f;
#pragma unroll
        for (int j = 0; j < 6; j++) { v[j] = xr[lane + 64 * j]; s += v[j]; q += v[j] * v[j]; }
#pragma unroll
        for (int off = 32; off; off >>= 1) { s += __shfl_xor(s, off); q += __shfl_xor(q, off); }
        float mean = s * (1.0f / DD);
        float var = q * (1.0f / DD) - mean * mean;
        float inv = 1.0f / sqrtf(var + 1e-5f);
#pragma unroll
        for (int j = 0; j < 6; j++) {
            int c = lane + 64 * j;
            pw[wave][c] += (v[j] - mean) * inv * ng[c] + nb[c];
        }
    }
    __syncthreads();
    float* out = pparts + ((size_t)b * 8 + chunk) * DD;
    for (int c = tid; c < DD; c += 256)
        out[c] = pw[0][c] + pw[1][c] + pw[2][c] + pw[3][c];
}

// ---------------------------------------------------------------- head MLP from pooled partials, one block per batch
__global__ __launch_bounds__(256) void k_mlp(const float* __restrict__ pparts,
    const float* __restrict__ w1, const float* __restrict__ b1,
    const float* __restrict__ w2, const float* __restrict__ b2,
    const float* __restrict__ w3, const float* __restrict__ b3,
    float* __restrict__ out)
{
    const int b = blockIdx.x, tid = threadIdx.x;
    __shared__ float pl[DD];
    __shared__ float h1[256];
    __shared__ float h2[64];
    for (int c = tid; c < DD; c += 256) {
        const float* pp = pparts + (size_t)b * 8 * DD + c;
        float s = 0.f;
#pragma unroll
        for (int z = 0; z < 8; z++) s += pp[z * DD];
        pl[c] = s * (1.0f / LL);
    }
    __syncthreads();

    {
        float acc = b1[tid];
        const float* wr = w1 + (size_t)tid * DD;
        for (int k = 0; k < DD; k++) acc += pl[k] * wr[k];
        h1[tid] = fmaxf(acc, 0.f);
    }
    __syncthreads();
    if (tid < 64) {
        float acc = b2[tid];
        const float* wr = w2 + (size_t)tid * 256;
        for (int k = 0; k < 256; k++) acc += h1[k] * wr[k];
        h2[tid] = fmaxf(acc, 0.f);
    }
    __syncthreads();
    if (tid < NC) {
        float acc = b3[tid];
        const float* wr = w3 + (size_t)tid * 64;
        for (int k = 0; k < 64; k++) acc += h2[k] * wr[k];
        out[b * NC + tid] = acc;
    }
}

// ---------------------------------------------------------------- launch
extern "C" void kernel_launch(void* const* d_in, const int* in_sizes, int n_in,
                              void* d_out, int out_size, void* d_ws, size_t ws_size,
                              hipStream_t stream)
{
    const float* data      = (const float*)d_in[0];
    const float* pe_w1     = (const float*)d_in[1];
    const float* pe_b1     = (const float*)d_in[2];
    const float* pe_g1     = (const float*)d_in[3];
    const float* pe_be1    = (const float*)d_in[4];
    const float* pe_w2     = (const float*)d_in[5];
    const float* pe_b2     = (const float*)d_in[6];
    const float* pe_g2     = (const float*)d_in[7];
    const float* pe_be2    = (const float*)d_in[8];
    const float* pe_w3     = (const float*)d_in[9];
    const float* pe_b3     = (const float*)d_in[10];
    const float* pe_g3     = (const float*)d_in[11];
    const float* pe_be3    = (const float*)d_in[12];
    const float* oi_h_scale  = (const float*)d_in[13];
    const float* oi_h_shift  = (const float*)d_in[14];
    const float* oi_th_scale = (const float*)d_in[15];
    const float* oi_th_shift = (const float*)d_in[16];
    const float* pos_embed = (const float*)d_in[17];
    const float* blk_ln_g  = (const float*)d_in[18];
    const float* blk_ln_b  = (const float*)d_in[19];
    const float* blk_in_w  = (const float*)d_in[20];
    const float* blk_conv_w = (const float*)d_in[21];
    const float* blk_conv_b = (const float*)d_in[22];
    const float* blk_xp_w  = (const float*)d_in[23];
    const float* blk_dt_w  = (const float*)d_in[24];
    const float* blk_dt_b  = (const float*)d_in[25];
    const float* blk_Alog  = (const float*)d_in[26];
    const float* blk_D     = (const float*)d_in[27];
    const float* blk_out_w = (const float*)d_in[28];
    const float* norm_g    = (const float*)d_in[29];
    const float* norm_b    = (const float*)d_in[30];
    const float* mlp_w1    = (const float*)d_in[31];
    const float* mlp_b1    = (const float*)d_in[32];
    const float* mlp_w2    = (const float*)d_in[33];
    const float* mlp_b2    = (const float*)d_in[34];
    const float* mlp_w3    = (const float*)d_in[35];
    const float* mlp_b3    = (const float*)d_in[36];

    float* ws = (float*)d_ws;
    size_t off = 0;
    auto alloc = [&](size_t n) { float* p = ws + off; off += (n + 63) & ~(size_t)63; return p; };
    float* tokens  = alloc((size_t)BB * PP * DD);
    float* centers = alloc((size_t)BB * PP * 3);
    float* t    = alloc((size_t)NR * DD);
    float* xdbl = alloc((size_t)NR * XROW);
    float* pparts  = alloc((size_t)BB * 8 * DD);
    int*   bar  = (int*)alloc(64);
    unsigned short* tbf   = (unsigned short*)alloc((size_t)NR * DD / 2);
    unsigned short* xcbf  = (unsigned short*)alloc((size_t)NR * DI / 2);
    unsigned short* zsbf  = (unsigned short*)alloc((size_t)NR * DI / 2);
    unsigned short* ybf   = (unsigned short*)alloc((size_t)NR * DI / 2);
    unsigned short* inwbf = (unsigned short*)alloc((size_t)DEPTH * 2 * DI * DD / 2);
    unsigned short* owbf  = (unsigned short*)alloc((size_t)DEPTH * DD * DI / 2);
    unsigned short* xpbf  = (unsigned short*)alloc((size_t)DEPTH * 64 * DI / 2);
    unsigned short* w3bf  = (unsigned short*)alloc((size_t)DD * 128 / 2);
    unsigned short* w2bf  = (unsigned short*)alloc((size_t)128 * 64 / 2);

    // one-shot weight conversion
    {
        const int total = DEPTH * 2 * DI * DD + DEPTH * DD * DI + DD * 128 + DEPTH * 64 * DI + 128 * 64;
        k_cvt<<<(total / 4 + 255) / 256, 256, 0, stream>>>(
            blk_in_w, blk_out_w, pe_w3, blk_xp_w, pe_w2, inwbf, owbf, w3bf, xpbf, w2bf);
    }

    k_patch<<<BB * PP, 256, 0, stream>>>(data,
        pe_w1, pe_b1, pe_g1, pe_be1, w2bf, pe_b2, pe_g2, pe_be2,
        w3bf, pe_b3, pe_g3, pe_be3, tokens, centers);
    k_sfc_build<<<dim3(24, BB), 256, 0, stream>>>(centers, tokens,
        oi_h_scale, oi_h_shift, oi_th_scale, oi_th_shift, pos_embed, t, bar);

    // ---- the whole 12-layer loop as ONE persistent kernel (plain launch, manual grid barrier)
    k_layers<<<GRID_G, 256, 0, stream>>>(
        t, xdbl, tbf, xcbf, zsbf, ybf,
        inwbf, owbf, xpbf,
        blk_ln_g, blk_ln_b, blk_conv_w, blk_conv_b,
        blk_dt_w, blk_dt_b, blk_Alog, blk_D, bar);

    k_lnpool<<<dim3(8, BB), 256, 0, stream>>>(t, norm_g, norm_b, pparts);
    k_mlp<<<BB, 256, 0, stream>>>(pparts, mlp_w1, mlp_b1, mlp_w2, mlp_b2, mlp_w3, mlp_b3,
                                  (float*)d_out);
}

// Round 9
// 937.581 us; speedup vs baseline: 5.1752x; 5.1752x over previous
//
#include <hip/hip_runtime.h>
#include <math.h>

#define BB 8
#define NN 2048
#define PP 64
#define KK 32
#define DD 384
#define DEPTH 12
#define DI 768
#define DS 16
#define DCONV 4
#define DTR 24
#define NC 40
#define LL 128  // 2*PP
#define XROW (DTR + 2 * DS)  // 56
#define NR (BB * LL)         // 1024

using bf16x8 = __attribute__((ext_vector_type(8))) short;
using floatx4 = __attribute__((ext_vector_type(4))) float;

// ---------------------------------------------------------------- helpers
__device__ __forceinline__ float gelu_exact(float x) {
    return 0.5f * x * (1.0f + erff(x * 0.70710678118654752440f));
}
__device__ __forceinline__ float siluf(float x) {
    return x / (1.0f + expf(-x));
}
__device__ __forceinline__ unsigned short f2bf(float f) {
    unsigned u = __float_as_uint(f);
    u += 0x7fffu + ((u >> 16) & 1u);   // round-to-nearest-even
    return (unsigned short)(u >> 16);
}
__device__ __forceinline__ float bf2f(short s) {
    return __uint_as_float(((unsigned)(unsigned short)s) << 16);
}
__device__ __forceinline__ unsigned spread_bits(unsigned v) {
    v &= 1023u;
    v = (v | (v << 16)) & 50331903u;
    v = (v | (v << 8)) & 50393103u;
    v = (v | (v << 4)) & 51130563u;
    v = (v | (v << 2)) & 153391689u;
    return v;
}

// ---------------------------------------------------------------- one-shot weight conversions (float4-vectorized)
__global__ void k_cvt(const float* __restrict__ in_w, const float* __restrict__ out_w,
                      const float* __restrict__ pe_w3, const float* __restrict__ xp,
                      const float* __restrict__ w2,
                      unsigned short* __restrict__ inwbf, unsigned short* __restrict__ owbf,
                      unsigned short* __restrict__ w3bf, unsigned short* __restrict__ xpbf,
                      unsigned short* __restrict__ w2bf)
{
    int idx = (blockIdx.x * 256 + threadIdx.x) * 4;
    const int n1 = DEPTH * 2 * DI * DD;
    const int n2 = DEPTH * DD * DI;
    const int n3 = DD * 128;
    const int n4 = DEPTH * 64 * DI;
    const int n5 = 128 * 64;
    if (idx < n1) {
        float4 v = *(const float4*)(in_w + idx);
        ushort4 o; o.x = f2bf(v.x); o.y = f2bf(v.y); o.z = f2bf(v.z); o.w = f2bf(v.w);
        *(ushort4*)(inwbf + idx) = o;
        return;
    }
    idx -= n1;
    if (idx < n2) {
        float4 v = *(const float4*)(out_w + idx);
        ushort4 o; o.x = f2bf(v.x); o.y = f2bf(v.y); o.z = f2bf(v.z); o.w = f2bf(v.w);
        *(ushort4*)(owbf + idx) = o;
        return;
    }
    idx -= n2;
    if (idx < n3) {
        float4 v = *(const float4*)(pe_w3 + idx);
        ushort4 o; o.x = f2bf(v.x); o.y = f2bf(v.y); o.z = f2bf(v.z); o.w = f2bf(v.w);
        *(ushort4*)(w3bf + idx) = o;
        return;
    }
    idx -= n3;
    if (idx < n4) {
        int i = idx / (64 * DI);
        int rem = idx - i * 64 * DI;
        int n = rem / DI, k = rem % DI;   // k multiple of 4, same row for all 4
        ushort4 o;
        if (n < XROW) {
            float4 v = *(const float4*)(xp + (size_t)i * XROW * DI + (size_t)n * DI + k);
            o.x = f2bf(v.x); o.y = f2bf(v.y); o.z = f2bf(v.z); o.w = f2bf(v.w);
        } else {
            o.x = o.y = o.z = o.w = 0;
        }
        *(ushort4*)(xpbf + (size_t)i * 64 * DI + (size_t)n * DI + k) = o;
        return;
    }
    idx -= n4;
    if (idx < n5) {
        float4 v = *(const float4*)(w2 + idx);
        ushort4 o; o.x = f2bf(v.x); o.y = f2bf(v.y); o.z = f2bf(v.z); o.w = f2bf(v.w);
        *(ushort4*)(w2bf + idx) = o;
    }
}

// ---------------------------------------------------------------- KNN (radix-select) + patch-embed MLP fused: one block per (b,p)
__global__ __launch_bounds__(256) void k_patch(
    const float* __restrict__ data,
    const float* __restrict__ w1, const float* __restrict__ b1,
    const float* __restrict__ g1, const float* __restrict__ be1,
    const unsigned short* __restrict__ w2bf, const float* __restrict__ b2,
    const float* __restrict__ g2, const float* __restrict__ be2,
    const unsigned short* __restrict__ w3bf, const float* __restrict__ b3,
    const float* __restrict__ g3, const float* __restrict__ be3,
    float* __restrict__ tokens, float* __restrict__ centers)
{
    const int bp = blockIdx.x;
    const int b = bp >> 6, p = bp & 63;
    const int tid = threadIdx.x;
    const float* X = data + (size_t)b * NN * 3;
    const float inv_den = 0.99999500003749968752f; // 1/sqrt(1+1e-5)

    __shared__ int hist[4][4][256];   // [round][wave][bin] -> zeroed once
    __shared__ int klist[KK];
    __shared__ int eqlist[256];
    __shared__ int s_kth, s_byte, s_cnt, s_eqcnt;
    __shared__ float nxs[KK * 3];
    __shared__ short h1b[KK][72];
    __shared__ short h2b[KK][136];

    const float cx = X[p * 32 * 3 + 0];
    const float cy = X[p * 32 * 3 + 1];
    const float cz = X[p * 32 * 3 + 2];
    if (tid == 0) {
        centers[(b * PP + p) * 3 + 0] = cx;
        centers[(b * PP + p) * 3 + 1] = cy;
        centers[(b * PP + p) * 3 + 2] = cz;
        s_kth = KK; s_cnt = 0; s_eqcnt = 0;
    }
    for (int i = tid; i < 4 * 4 * 256; i += 256) ((int*)hist)[i] = 0;

    const int wave = tid >> 6, lane = tid & 63;

    // ---- KNN phase: radix-select the 32 smallest d2 keys
    {
        unsigned key[8];
#pragma unroll
        for (int q = 0; q < 8; q++) {
            int i = tid + 256 * q;
            float dx = cx - X[i * 3 + 0];
            float dy = cy - X[i * 3 + 1];
            float dz = cz - X[i * 3 + 2];
            float d2 = dx * dx + dy * dy + dz * dz;
            key[q] = __float_as_uint(d2);
        }
        __syncthreads();
        unsigned prefix = 0;
        for (int rnd = 3; rnd >= 0; rnd--) {
            const int sh = rnd * 8;
            const int rslot = 3 - rnd;
            const unsigned pmask = (rnd == 3) ? 0u : (0xFFFFFFFFu << (8 * (rnd + 1)));
#pragma unroll
            for (int q = 0; q < 8; q++)
                if ((key[q] & pmask) == prefix)
                    atomicAdd(&hist[rslot][wave][(key[q] >> sh) & 255], 1);
            __syncthreads();
            if (wave == 0) {
                int c[4], tot = 0;
#pragma unroll
                for (int j = 0; j < 4; j++) {
                    int s4 = 0;
#pragma unroll
                    for (int w = 0; w < 4; w++) s4 += hist[rslot][w][lane * 4 + j];
                    c[j] = s4; tot += s4;
                }
                int inc = tot;
#pragma unroll
                for (int off = 1; off < 64; off <<= 1) {
                    int u = __shfl_up(inc, off);
                    if (lane >= off) inc += u;
                }
                int exc = inc - tot;
                int kth = s_kth;
                bool has = (exc < kth) && (exc + tot >= kth);
                unsigned long long bal = __ballot(has);
                int src = __ffsll(bal) - 1;
                if (lane == src) {
                    int rem = kth - exc;
                    int j = 0, cum = 0;
                    while (cum + c[j] < rem) { cum += c[j]; j++; }
                    s_byte = lane * 4 + j;
                    s_kth = rem - cum;
                }
            }
            __syncthreads();
            prefix |= ((unsigned)s_byte) << sh;
        }
        const unsigned kstar = prefix;
        const int need = s_kth;
#pragma unroll
        for (int q = 0; q < 8; q++) {
            int i = tid + 256 * q;
            if (key[q] < kstar) {
                int pos = atomicAdd(&s_cnt, 1);
                klist[pos] = i;
            } else if (key[q] == kstar) {
                int pos = atomicAdd(&s_eqcnt, 1);
                if (pos < 256) eqlist[pos] = i;
            }
        }
        __syncthreads();
        if (tid == 0) {
            int base = s_cnt;
            int ne = s_eqcnt < 256 ? s_eqcnt : 256;
            for (int k = 0; k < need; k++) {
                int best = 0x7fffffff, bi = 0;
                for (int j = 0; j < ne; j++)
                    if (eqlist[j] < best) { best = eqlist[j]; bi = j; }
                klist[base + k] = best;
                eqlist[bi] = 0x7fffffff;
            }
        }
        __syncthreads();
    }

    // ---- patch-embed MLP phase
    if (tid < KK) {
        int q = klist[tid];
        nxs[tid * 3 + 0] = X[q * 3 + 0] - cx;
        nxs[tid * 3 + 1] = X[q * 3 + 1] - cy;
        nxs[tid * 3 + 2] = X[q * 3 + 2] - cz;
    }
    __syncthreads();

    for (int e = tid; e < KK * 64; e += 256) {
        int j = e >> 6, c = e & 63;
        float v = nxs[j * 3 + 0] * w1[c * 3 + 0] + nxs[j * 3 + 1] * w1[c * 3 + 1] +
                  nxs[j * 3 + 2] * w1[c * 3 + 2] + b1[c];
        v = v * (g1[c] * inv_den) + be1[c];
        h1b[j][c] = (short)f2bf(gelu_exact(v));
    }
    __syncthreads();

    const int quad = lane >> 4, r = lane & 15;

    // layer 2: 64 -> 128 via MFMA
    {
        floatx4 acc2[2][2] = {};
#pragma unroll
        for (int ks = 0; ks < 2; ks++) {
            const int k0 = ks * 32;
            bf16x8 af[2], bfv[2];
#pragma unroll
            for (int mi = 0; mi < 2; mi++)
                af[mi] = *(const bf16x8*)&h1b[mi * 16 + r][quad * 8 + k0];
#pragma unroll
            for (int jj = 0; jj < 2; jj++) {
                int n = wave * 32 + jj * 16 + r;
                bfv[jj] = *(const bf16x8*)(w2bf + (size_t)n * 64 + quad * 8 + k0);
            }
#pragma unroll
            for (int mi = 0; mi < 2; mi++)
#pragma unroll
                for (int jj = 0; jj < 2; jj++)
                    acc2[mi][jj] = __builtin_amdgcn_mfma_f32_16x16x32_bf16(af[mi], bfv[jj], acc2[mi][jj], 0, 0, 0);
        }
#pragma unroll
        for (int jj = 0; jj < 2; jj++) {
            int col = wave * 32 + jj * 16 + r;
            float sc = g2[col] * inv_den;
            float bb = b2[col] * sc + be2[col];
#pragma unroll
            for (int mi = 0; mi < 2; mi++)
#pragma unroll
                for (int r2 = 0; r2 < 4; r2++) {
                    int row = mi * 16 + quad * 4 + r2;
                    h2b[row][col] = (short)f2bf(gelu_exact(acc2[mi][jj][r2] * sc + bb));
                }
        }
    }
    __syncthreads();

    // layer 3: 128 -> 384 via MFMA + max over K
    floatx4 acc3[2][6] = {};
#pragma unroll
    for (int ks = 0; ks < 4; ks++) {
        const int k0 = ks * 32;
        bf16x8 af[2];
        af[0] = *(const bf16x8*)&h2b[r][quad * 8 + k0];
        af[1] = *(const bf16x8*)&h2b[16 + r][quad * 8 + k0];
        bf16x8 bfv[6];
#pragma unroll
        for (int nj = 0; nj < 6; nj++) {
            int n = wave * 96 + nj * 16 + r;
            bfv[nj] = *(const bf16x8*)(w3bf + (size_t)n * 128 + quad * 8 + k0);
        }
#pragma unroll
        for (int mi = 0; mi < 2; mi++)
#pragma unroll
            for (int nj = 0; nj < 6; nj++)
                acc3[mi][nj] = __builtin_amdgcn_mfma_f32_16x16x32_bf16(af[mi], bfv[nj], acc3[mi][nj], 0, 0, 0);
    }
#pragma unroll
    for (int nj = 0; nj < 6; nj++) {
        int col = wave * 96 + nj * 16 + r;
        float sc = g3[col] * inv_den;
        float offc = b3[col] * sc + be3[col];
        float m = -3.4e38f;
#pragma unroll
        for (int mi = 0; mi < 2; mi++)
#pragma unroll
            for (int r2 = 0; r2 < 4; r2++)
                m = fmaxf(m, acc3[mi][nj][r2] * sc + offc);
        m = fmaxf(m, __shfl_xor(m, 16));
        m = fmaxf(m, __shfl_xor(m, 32));
        if (quad == 0) tokens[(size_t)bp * DD + col] = m;
    }
}

// ---------------------------------------------------------------- SFC orders + build token sequence fused.
__global__ __launch_bounds__(256) void k_sfc_build(
    const float* __restrict__ centers, const float* __restrict__ tokens,
    const float* __restrict__ hs, const float* __restrict__ hb,
    const float* __restrict__ ts2, const float* __restrict__ tb2,
    const float* __restrict__ pos, float* __restrict__ tout)
{
    const int b = blockIdx.y, part = blockIdx.x;
    const int tid = threadIdx.x;

    __shared__ float csh[PP][3];
    __shared__ float slo[3], shi[3];
    __shared__ unsigned khs[PP], kts[PP];
    __shared__ int oh[PP], ot[PP];

    if (tid < PP) {
        csh[tid][0] = centers[(b * PP + tid) * 3 + 0];
        csh[tid][1] = centers[(b * PP + tid) * 3 + 1];
        csh[tid][2] = centers[(b * PP + tid) * 3 + 2];
    }
    __syncthreads();
    if (tid == 0) {
        for (int k = 0; k < 3; k++) {
            float lo = csh[0][k], hi = csh[0][k];
            for (int j = 1; j < PP; j++) { lo = fminf(lo, csh[j][k]); hi = fmaxf(hi, csh[j][k]); }
            slo[k] = lo; shi[k] = hi;
        }
    }
    __syncthreads();
    if (tid < PP) {
        int q[3];
        for (int k = 0; k < 3; k++) {
            float t = (csh[tid][k] - slo[k]) / (shi[k] - slo[k] + 1e-6f) * 1023.0f;
            int qi = (int)t;
            qi = qi < 0 ? 0 : (qi > 1023 ? 1023 : qi);
            q[k] = qi;
        }
        khs[tid] = spread_bits((unsigned)q[0]) | (spread_bits((unsigned)q[1]) << 1) |
                   (spread_bits((unsigned)q[2]) << 2);
        kts[tid] = spread_bits((unsigned)q[2]) | (spread_bits((unsigned)q[1]) << 1) |
                   (spread_bits((unsigned)q[0]) << 2);
    }
    __syncthreads();
    if (tid < PP) {
        unsigned kh = khs[tid], kt = kts[tid];
        int rh = 0, rt = 0;
        for (int j = 0; j < PP; j++) {
            unsigned a = khs[j];
            rh += (a < kh) || (a == kh && j < tid);
            unsigned c = kts[j];
            rt += (c < kt) || (c == kt && j < tid);
        }
        oh[rh] = tid;
        ot[rt] = tid;
    }
    __syncthreads();

    const int base = part * (LL * DD / 24);  // 2048-element slice
    for (int e = tid; e < LL * DD / 24; e += 256) {
        int idx = base + e;
        int d = idx % DD;
        int l = idx / DD;
        float v;
        if (l < PP) {
            int src = oh[l];
            v = tokens[((size_t)b * PP + src) * DD + d] * hs[d] + hb[d] + pos[l * DD + d];
        } else {
            int l2 = l - PP;
            int src = ot[l2];
            v = tokens[((size_t)b * PP + src) * DD + d] * ts2[d] + tb2[d] + pos[l2 * DD + d];
        }
        tout[(size_t)b * LL * DD + idx] = v;
    }
}

// ---------------------------------------------------------------- LN: t -> tbf (bf16), one wave per row; also zero xdbl
__global__ __launch_bounds__(256) void k_stats(const float* __restrict__ t,
                                               const float* __restrict__ g,
                                               const float* __restrict__ gb,
                                               unsigned short* __restrict__ tbf,
                                               float* __restrict__ xdbl)
{
    const int tid = threadIdx.x;
    {
        int gi = blockIdx.x * 256 + tid;
        if (gi < NR * XROW) xdbl[gi] = 0.f;
    }
    const int wid = tid >> 6, lane = tid & 63;
    const int row = blockIdx.x * 4 + wid;
    const size_t base = (size_t)row * DD;
    float v[6];
    float s = 0.f, q = 0.f;
#pragma unroll
    for (int j = 0; j < 6; j++) {
        v[j] = t[base + lane + 64 * j];
        s += v[j]; q += v[j] * v[j];
    }
#pragma unroll
    for (int off = 32; off; off >>= 1) { s += __shfl_xor(s, off); q += __shfl_xor(q, off); }
    float mean = s * (1.0f / DD);
    float var = q * (1.0f / DD) - mean * mean;
    float inv = 1.0f / sqrtf(var + 1e-5f);
#pragma unroll
    for (int j = 0; j < 6; j++) {
        int i = lane + 64 * j;
        tbf[base + i] = f2bf((v[j] - mean) * inv * g[i] + gb[i]);
    }
}

// ---------------------------------------------------------------- xz MFMA GEMM (128 tokens x 64 cols) + fused conv/SiLU
// + fused xdbl split-K partial via atomicAdd.  grid (24, 8) x 512 thr: 8 waves, each a 32x32 quadrant.
__global__ __launch_bounds__(512) void k_mfma_xz(
    const unsigned short* __restrict__ tbf,
    const unsigned short* __restrict__ inwbf,
    const float* __restrict__ cw, const float* __restrict__ cb,
    const unsigned short* __restrict__ xpbf,
    unsigned short* __restrict__ xcbf, unsigned short* __restrict__ zsbf,
    float* __restrict__ xdbl)
{
    __shared__ short ct[128][72];   // 64 cols + 8 pad
    const int tid = threadIdx.x;
    const int wave = tid >> 6, lane = tid & 63;
    const int quad = lane >> 4, r = lane & 15;
    const int wm = wave >> 1, wn = wave & 1;   // wm 0..3 (32-row bands), wn 0..1 (32-col bands)
    const int b = blockIdx.y;
    const int n0 = blockIdx.x * 64;
    const int m0 = b * 128 + wm * 32;

    floatx4 acc[2][2] = {};
    const unsigned short* Ab = tbf + (size_t)(m0 + r) * DD + quad * 8;
    const unsigned short* Bb = inwbf + (size_t)(n0 + wn * 32 + r) * DD + quad * 8;
    for (int k0 = 0; k0 < DD; k0 += 32) {
        bf16x8 af[2], bfv[2];
#pragma unroll
        for (int i = 0; i < 2; i++)
            af[i] = *(const bf16x8*)(Ab + (size_t)(i * 16) * DD + k0);
#pragma unroll
        for (int j = 0; j < 2; j++)
            bfv[j] = *(const bf16x8*)(Bb + (size_t)(j * 16) * DD + k0);
#pragma unroll
        for (int i = 0; i < 2; i++)
#pragma unroll
            for (int j = 0; j < 2; j++)
                acc[i][j] = __builtin_amdgcn_mfma_f32_16x16x32_bf16(af[i], bfv[j], acc[i][j], 0, 0, 0);
    }

    // C -> LDS (bf16).  row = wm*32 + i*16 + quad*4 + r2, col = wn*32 + j*16 + r
#pragma unroll
    for (int i = 0; i < 2; i++)
#pragma unroll
        for (int r2 = 0; r2 < 4; r2++) {
            short* cp = &ct[wm * 32 + i * 16 + quad * 4 + r2][wn * 32 + r];
#pragma unroll
            for (int j = 0; j < 2; j++)
                cp[j * 16] = (short)f2bf(acc[i][j][r2]);
        }
    __syncthreads();

    const int l0 = (tid >> 3) * 2;      // 2 rows per thread (512 thr)
    const int c0 = (tid & 7) * 8;       // 8 cols per thread
    if (n0 < DI) {
        float cwv[8][4], cbv[8];
#pragma unroll
        for (int q = 0; q < 8; q++) {
            *(float4*)cwv[q] = *(const float4*)(cw + (size_t)(n0 + c0 + q) * 4);
            cbv[q] = cb[n0 + c0 + q];
        }
        unsigned short ov[2][8];
#pragma unroll
        for (int dl = 0; dl < 2; dl++) {
            const int l = l0 + dl;
            float u[8];
#pragma unroll
            for (int q = 0; q < 8; q++) u[q] = cbv[q];
#pragma unroll
            for (int j = 0; j < DCONV; j++) {
                int lt = l - (DCONV - 1) + j;
                if (lt >= 0) {
                    bf16x8 x = *(const bf16x8*)&ct[lt][c0];
#pragma unroll
                    for (int q = 0; q < 8; q++) u[q] += bf2f(x[q]) * cwv[q][j];
                }
            }
#pragma unroll
            for (int q = 0; q < 8; q++) ov[dl][q] = f2bf(siluf(u[q]));
        }
        __syncthreads();   // all pre-conv reads done
#pragma unroll
        for (int dl = 0; dl < 2; dl++) {
            const int l = l0 + dl;
            *(bf16x8*)&ct[l][c0] = *(bf16x8*)ov[dl];
            *(bf16x8*)(xcbf + (size_t)(b * LL + l) * DI + n0 + c0) = *(bf16x8*)ov[dl];
        }
        __syncthreads();

        // fused xdbl partial: K = 64 (this block's channel slice), 8 waves x 16 rows
        floatx4 acc2[4] = {};
#pragma unroll
        for (int k0 = 0; k0 < 64; k0 += 32) {
            bf16x8 af2 = *(const bf16x8*)&ct[wave * 16 + r][k0 + quad * 8];
            bf16x8 bfv2[4];
#pragma unroll
            for (int nj = 0; nj < 4; nj++)
                bfv2[nj] = *(const bf16x8*)(xpbf + (size_t)(nj * 16 + r) * DI + n0 + k0 + quad * 8);
#pragma unroll
            for (int nj = 0; nj < 4; nj++)
                acc2[nj] = __builtin_amdgcn_mfma_f32_16x16x32_bf16(af2, bfv2[nj], acc2[nj], 0, 0, 0);
        }
#pragma unroll
        for (int nj = 0; nj < 4; nj++) {
            int col = nj * 16 + r;
            if (col < XROW) {
#pragma unroll
                for (int r2 = 0; r2 < 4; r2++) {
                    int row = b * LL + wave * 16 + quad * 4 + r2;
                    unsafeAtomicAdd(&xdbl[(size_t)row * XROW + col], acc2[nj][r2]);
                }
            }
        }
    } else {
        const int nz = n0 - DI;
#pragma unroll
        for (int dl = 0; dl < 2; dl++) {
            const int l = l0 + dl;
            bf16x8 x = *(const bf16x8*)&ct[l][c0];
            unsigned short o[8];
#pragma unroll
            for (int q = 0; q < 8; q++) o[q] = f2bf(siluf(bf2f(x[q])));
            *(bf16x8*)(zsbf + (size_t)(b * LL + l) * DI + nz + c0) = *(bf16x8*)o;
        }
    }
}

// ---------------------------------------------------------------- chunk-parallel selective scan (1 channel / 128-thr block)
__global__ __launch_bounds__(128) void k_scan(
    const float* __restrict__ xdbl,
    const unsigned short* __restrict__ xcbf, const unsigned short* __restrict__ zsbf,
    const float* __restrict__ dtw, const float* __restrict__ dtb,
    const float* __restrict__ Alog, const float* __restrict__ Dp,
    unsigned short* __restrict__ ybf)
{
    const int tid = threadIdx.x;
    const int b = blockIdx.x / DI;
    const int d = blockIdx.x % DI;

    __shared__ float sdel[LL];
    __shared__ float sdus[LL];
    __shared__ float sus[LL];
    __shared__ float szs[LL];
    __shared__ float negA[DS];
    __shared__ float ApL[DS][9];
    __shared__ float HlL[DS][9];
    __shared__ float hst[DS][9];

    // phase 1: per-token scalars (t = tid)
    {
        const int t = tid;
        const size_t row = (size_t)b * LL + t;
        const float* xd = xdbl + row * XROW;
        const float* w = dtw + d * DTR;
        float acc = dtb[d];
#pragma unroll
        for (int k = 0; k < DTR; k += 4) {
            float4 xv = *(const float4*)(xd + k);
            float4 wv = *(const float4*)(w + k);
            acc += xv.x * wv.x + xv.y * wv.y + xv.z * wv.z + xv.w * wv.w;
        }
        float delta = fmaxf(acc, 0.f) + log1pf(__expf(-fabsf(acc)));  // softplus
        float u = bf2f((short)xcbf[row * DI + d]);
        sdel[t] = delta;
        sdus[t] = delta * u;
        sus[t] = u;
        szs[t] = bf2f((short)zsbf[row * DI + d]);
    }
    if (tid < DS) negA[tid] = -__expf(Alog[d * DS + tid]);
    __syncthreads();

    const int s = tid & 15;
    const int c = tid >> 4;           // chunk 0..7
    const float* xB = xdbl + ((size_t)b * LL + c * 16) * XROW + DTR + s;

    float a_r[16], duB_r[16], C_r[16];
    {
        float h = 0.f, Ap = 1.f;
        const float na = negA[s];
#pragma unroll
        for (int q = 0; q < 16; q++) {
            int t = c * 16 + q;
            float a = __expf(sdel[t] * na);
            float Bv = xB[(size_t)q * XROW];
            float Cv = xB[(size_t)q * XROW + DS];
            a_r[q] = a;
            duB_r[q] = sdus[t] * Bv;
            C_r[q] = Cv;
            h = h * a + duB_r[q];
            Ap *= a;
        }
        ApL[s][c] = Ap;
        HlL[s][c] = h;
    }
    __syncthreads();
    if (tid < DS) {
        float hs = 0.f;
#pragma unroll
        for (int cc = 0; cc < 8; cc++) {
            hst[tid][cc] = hs;
            hs = ApL[tid][cc] * hs + HlL[tid][cc];
        }
    }
    __syncthreads();

    {
        const float Dd = Dp[d];
        float h = hst[s][c];
        unsigned short* yc = ybf + ((size_t)b * LL + c * 16) * DI + d;
#pragma unroll
        for (int q = 0; q < 16; q++) {
            h = h * a_r[q] + duB_r[q];
            float p = h * C_r[q];
            p += __shfl_xor(p, 1, 16);
            p += __shfl_xor(p, 2, 16);
            p += __shfl_xor(p, 4, 16);
            p += __shfl_xor(p, 8, 16);
            if (s == 0) {
                int t = c * 16 + q;
                yc[(size_t)q * DI] = f2bf((p + Dd * sus[t]) * szs[t]);
            }
        }
    }
}

// ---------------------------------------------------------------- out-proj MFMA GEMM, split-K=2, atomic residual RMW on t.
// grid (6, 32, 2): x = 64-col tile, y = 32-row tile, z = K-half (384 each).
__global__ __launch_bounds__(256) void k_mfma_op(
    const unsigned short* __restrict__ ybf,
    const unsigned short* __restrict__ owbf,
    float* __restrict__ t)
{
    const int tid = threadIdx.x;
    const int wave = tid >> 6, lane = tid & 63;
    const int quad = lane >> 4, r = lane & 15;
    const int wr2 = wave >> 1, wc = wave & 1;
    const int n0 = blockIdx.x * 64 + wc * 32;
    const int m0 = blockIdx.y * 32 + wr2 * 16;
    const int kb = blockIdx.z * (DI / 2);

    floatx4 acc[2] = {};
    const unsigned short* Ab = ybf + (size_t)(m0 + r) * DI + kb + quad * 8;
    const unsigned short* Bb = owbf + (size_t)(n0 + r) * DI + kb + quad * 8;
    for (int k0 = 0; k0 < DI / 2; k0 += 32) {
        bf16x8 af = *(const bf16x8*)(Ab + k0);
        bf16x8 b0 = *(const bf16x8*)(Bb + k0);
        bf16x8 b1 = *(const bf16x8*)(Bb + (size_t)16 * DI + k0);
        acc[0] = __builtin_amdgcn_mfma_f32_16x16x32_bf16(af, b0, acc[0], 0, 0, 0);
        acc[1] = __builtin_amdgcn_mfma_f32_16x16x32_bf16(af, b1, acc[1], 0, 0, 0);
    }

#pragma unroll
    for (int j = 0; j < 2; j++) {
        int col = n0 + j * 16 + r;
#pragma unroll
        for (int r2 = 0; r2 < 4; r2++) {
            int row = m0 + quad * 4 + r2;
            unsafeAtomicAdd(t + (size_t)row * DD + col, acc[j][r2]);
        }
    }
}

// ---------------------------------------------------------------- final LN + partial mean-pool: grid (8 chunks, 8 batches)
__global__ __launch_bounds__(256) void k_lnpool(const float* __restrict__ t,
                                                const float* __restrict__ ng,
                                                const float* __restrict__ nb,
                                                float* __restrict__ pparts)  // [BB][8][DD]
{
    const int b = blockIdx.y, chunk = blockIdx.x;
    const int tid = threadIdx.x;
    const int wave = tid >> 6, lane = tid & 63;
    __shared__ float pw[4][DD];

    for (int c = lane; c < DD; c += 64) pw[wave][c] = 0.f;
    __syncthreads();

    for (int rr = 0; rr < 4; rr++) {
        const int row = b * LL + chunk * 16 + wave * 4 + rr;
        const float* xr = t + (size_t)row * DD;
        float v[6];
        float s = 0.f, q = 0.f;
#pragma unroll
        for (int j = 0; j < 6; j++) { v[j] = xr[lane + 64 * j]; s += v[j]; q += v[j] * v[j]; }
#pragma unroll
        for (int off = 32; off; off >>= 1) { s += __shfl_xor(s, off); q += __shfl_xor(q, off); }
        float mean = s * (1.0f / DD);
        float var = q * (1.0f / DD) - mean * mean;
        float inv = 1.0f / sqrtf(var + 1e-5f);
#pragma unroll
        for (int j = 0; j < 6; j++) {
            int c = lane + 64 * j;
            pw[wave][c] += (v[j] - mean) * inv * ng[c] + nb[c];
        }
    }
    __syncthreads();
    float* out = pparts + ((size_t)b * 8 + chunk) * DD;
    for (int c = tid; c < DD; c += 256)
        out[c] = pw[0][c] + pw[1][c] + pw[2][c] + pw[3][c];
}

// ---------------------------------------------------------------- head MLP from pooled partials, one block per batch
__global__ __launch_bounds__(256) void k_mlp(const float* __restrict__ pparts,
    const float* __restrict__ w1, const float* __restrict__ b1,
    const float* __restrict__ w2, const float* __restrict__ b2,
    const float* __restrict__ w3, const float* __restrict__ b3,
    float* __restrict__ out)
{
    const int b = blockIdx.x, tid = threadIdx.x;
    __shared__ float pl[DD];
    __shared__ float h1[256];
    __shared__ float h2[64];
    for (int c = tid; c < DD; c += 256) {
        const float* pp = pparts + (size_t)b * 8 * DD + c;
        float s = 0.f;
#pragma unroll
        for (int z = 0; z < 8; z++) s += pp[z * DD];
        pl[c] = s * (1.0f / LL);
    }
    __syncthreads();

    {
        float acc = b1[tid];
        const float* wr = w1 + (size_t)tid * DD;
        for (int k = 0; k < DD; k++) acc += pl[k] * wr[k];
        h1[tid] = fmaxf(acc, 0.f);
    }
    __syncthreads();
    if (tid < 64) {
        float acc = b2[tid];
        const float* wr = w2 + (size_t)tid * 256;
        for (int k = 0; k < 256; k++) acc += h1[k] * wr[k];
        h2[tid] = fmaxf(acc, 0.f);
    }
    __syncthreads();
    if (tid < NC) {
        float acc = b3[tid];
        const float* wr = w3 + (size_t)tid * 64;
        for (int k = 0; k < 64; k++) acc += h2[k] * wr[k];
        out[b * NC + tid] = acc;
    }
}

// ---------------------------------------------------------------- launch
extern "C" void kernel_launch(void* const* d_in, const int* in_sizes, int n_in,
                              void* d_out, int out_size, void* d_ws, size_t ws_size,
                              hipStream_t stream)
{
    const float* data      = (const float*)d_in[0];
    const float* pe_w1     = (const float*)d_in[1];
    const float* pe_b1     = (const float*)d_in[2];
    const float* pe_g1     = (const float*)d_in[3];
    const float* pe_be1    = (const float*)d_in[4];
    const float* pe_w2     = (const float*)d_in[5];
    const float* pe_b2     = (const float*)d_in[6];
    const float* pe_g2     = (const float*)d_in[7];
    const float* pe_be2    = (const float*)d_in[8];
    const float* pe_w3     = (const float*)d_in[9];
    const float* pe_b3     = (const float*)d_in[10];
    const float* pe_g3     = (const float*)d_in[11];
    const float* pe_be3    = (const float*)d_in[12];
    const float* oi_h_scale  = (const float*)d_in[13];
    const float* oi_h_shift  = (const float*)d_in[14];
    const float* oi_th_scale = (const float*)d_in[15];
    const float* oi_th_shift = (const float*)d_in[16];
    const float* pos_embed = (const float*)d_in[17];
    const float* blk_ln_g  = (const float*)d_in[18];
    const float* blk_ln_b  = (const float*)d_in[19];
    const float* blk_in_w  = (const float*)d_in[20];
    const float* blk_conv_w = (const float*)d_in[21];
    const float* blk_conv_b = (const float*)d_in[22];
    const float* blk_xp_w  = (const float*)d_in[23];
    const float* blk_dt_w  = (const float*)d_in[24];
    const float* blk_dt_b  = (const float*)d_in[25];
    const float* blk_Alog  = (const float*)d_in[26];
    const float* blk_D     = (const float*)d_in[27];
    const float* blk_out_w = (const float*)d_in[28];
    const float* norm_g    = (const float*)d_in[29];
    const float* norm_b    = (const float*)d_in[30];
    const float* mlp_w1    = (const float*)d_in[31];
    const float* mlp_b1    = (const float*)d_in[32];
    const float* mlp_w2    = (const float*)d_in[33];
    const float* mlp_b2    = (const float*)d_in[34];
    const float* mlp_w3    = (const float*)d_in[35];
    const float* mlp_b3    = (const float*)d_in[36];

    float* ws = (float*)d_ws;
    size_t off = 0;
    auto alloc = [&](size_t n) { float* p = ws + off; off += (n + 63) & ~(size_t)63; return p; };
    float* tokens  = alloc((size_t)BB * PP * DD);
    float* centers = alloc((size_t)BB * PP * 3);
    float* t    = alloc((size_t)NR * DD);
    float* xdbl = alloc((size_t)NR * XROW);
    float* pparts  = alloc((size_t)BB * 8 * DD);
    unsigned short* tbf   = (unsigned short*)alloc((size_t)NR * DD / 2);
    unsigned short* xcbf  = (unsigned short*)alloc((size_t)NR * DI / 2);
    unsigned short* zsbf  = (unsigned short*)alloc((size_t)NR * DI / 2);
    unsigned short* ybf   = (unsigned short*)alloc((size_t)NR * DI / 2);
    unsigned short* inwbf = (unsigned short*)alloc((size_t)DEPTH * 2 * DI * DD / 2);
    unsigned short* owbf  = (unsigned short*)alloc((size_t)DEPTH * DD * DI / 2);
    unsigned short* xpbf  = (unsigned short*)alloc((size_t)DEPTH * 64 * DI / 2);
    unsigned short* w3bf  = (unsigned short*)alloc((size_t)DD * 128 / 2);
    unsigned short* w2bf  = (unsigned short*)alloc((size_t)128 * 64 / 2);

    // one-shot weight conversion (all five targets, 4 elems/thread)
    {
        const int total = DEPTH * 2 * DI * DD + DEPTH * DD * DI + DD * 128 + DEPTH * 64 * DI + 128 * 64;
        k_cvt<<<(total / 4 + 255) / 256, 256, 0, stream>>>(
            blk_in_w, blk_out_w, pe_w3, blk_xp_w, pe_w2, inwbf, owbf, w3bf, xpbf, w2bf);
    }

    k_patch<<<BB * PP, 256, 0, stream>>>(data,
        pe_w1, pe_b1, pe_g1, pe_be1, w2bf, pe_b2, pe_g2, pe_be2,
        w3bf, pe_b3, pe_g3, pe_be3, tokens, centers);
    k_sfc_build<<<dim3(24, BB), 256, 0, stream>>>(centers, tokens,
        oi_h_scale, oi_h_shift, oi_th_scale, oi_th_shift, pos_embed, t);

    for (int i = 0; i < DEPTH; i++) {
        const float* ln_g = blk_ln_g + i * DD;
        const float* ln_b = blk_ln_b + i * DD;
        const float* cw   = blk_conv_w + (size_t)i * DI * DCONV;
        const float* cb   = blk_conv_b + (size_t)i * DI;
        const float* dtw  = blk_dt_w + (size_t)i * DI * DTR;
        const float* dtb  = blk_dt_b + (size_t)i * DI;
        const float* Al   = blk_Alog + (size_t)i * DI * DS;
        const float* Dpp  = blk_D + (size_t)i * DI;
        const unsigned short* inw = inwbf + (size_t)i * 2 * DI * DD;
        const unsigned short* ow  = owbf + (size_t)i * DD * DI;
        const unsigned short* xpb = xpbf + (size_t)i * 64 * DI;

        k_stats<<<NR / 4, 256, 0, stream>>>(t, ln_g, ln_b, tbf, xdbl);
        k_mfma_xz<<<dim3(24, BB), 512, 0, stream>>>(
            tbf, inw, cw, cb, xpb, xcbf, zsbf, xdbl);
        k_scan<<<BB * DI, 128, 0, stream>>>(xdbl, xcbf, zsbf, dtw, dtb, Al, Dpp, ybf);
        k_mfma_op<<<dim3(DD / 64, NR / 32, 2), 256, 0, stream>>>(ybf, ow, t);
    }

    k_lnpool<<<dim3(8, BB), 256, 0, stream>>>(t, norm_g, norm_b, pparts);
    k_mlp<<<BB, 256, 0, stream>>>(pparts, mlp_w1, mlp_b1, mlp_w2, mlp_b2, mlp_w3, mlp_b3,
                                  (float*)d_out);
}

// Round 10
// 914.655 us; speedup vs baseline: 5.3050x; 1.0251x over previous
//
#include <hip/hip_runtime.h>
#include <math.h>

#define BB 8
#define NN 2048
#define PP 64
#define KK 32
#define DD 384
#define DEPTH 12
#define DI 768
#define DS 16
#define DCONV 4
#define DTR 24
#define NC 40
#define LL 128  // 2*PP
#define XROW (DTR + 2 * DS)  // 56
#define NR (BB * LL)         // 1024

using bf16x8 = __attribute__((ext_vector_type(8))) short;
using floatx4 = __attribute__((ext_vector_type(4))) float;

// ---------------------------------------------------------------- helpers
__device__ __forceinline__ float gelu_exact(float x) {
    return 0.5f * x * (1.0f + erff(x * 0.70710678118654752440f));
}
__device__ __forceinline__ float siluf(float x) {
    return x / (1.0f + expf(-x));
}
__device__ __forceinline__ unsigned short f2bf(float f) {
    unsigned u = __float_as_uint(f);
    u += 0x7fffu + ((u >> 16) & 1u);   // round-to-nearest-even
    return (unsigned short)(u >> 16);
}
__device__ __forceinline__ float bf2f(short s) {
    return __uint_as_float(((unsigned)(unsigned short)s) << 16);
}
__device__ __forceinline__ unsigned spread_bits(unsigned v) {
    v &= 1023u;
    v = (v | (v << 16)) & 50331903u;
    v = (v | (v << 8)) & 50393103u;
    v = (v | (v << 4)) & 51130563u;
    v = (v | (v << 2)) & 153391689u;
    return v;
}

// ---------------------------------------------------------------- one-shot weight conversions (float4-vectorized)
__global__ void k_cvt(const float* __restrict__ in_w, const float* __restrict__ out_w,
                      const float* __restrict__ pe_w3, const float* __restrict__ xp,
                      const float* __restrict__ w2,
                      unsigned short* __restrict__ inwbf, unsigned short* __restrict__ owbf,
                      unsigned short* __restrict__ w3bf, unsigned short* __restrict__ xpbf,
                      unsigned short* __restrict__ w2bf)
{
    int idx = (blockIdx.x * 256 + threadIdx.x) * 4;
    const int n1 = DEPTH * 2 * DI * DD;
    const int n2 = DEPTH * DD * DI;
    const int n3 = DD * 128;
    const int n4 = DEPTH * 64 * DI;
    const int n5 = 128 * 64;
    if (idx < n1) {
        float4 v = *(const float4*)(in_w + idx);
        ushort4 o; o.x = f2bf(v.x); o.y = f2bf(v.y); o.z = f2bf(v.z); o.w = f2bf(v.w);
        *(ushort4*)(inwbf + idx) = o;
        return;
    }
    idx -= n1;
    if (idx < n2) {
        float4 v = *(const float4*)(out_w + idx);
        ushort4 o; o.x = f2bf(v.x); o.y = f2bf(v.y); o.z = f2bf(v.z); o.w = f2bf(v.w);
        *(ushort4*)(owbf + idx) = o;
        return;
    }
    idx -= n2;
    if (idx < n3) {
        float4 v = *(const float4*)(pe_w3 + idx);
        ushort4 o; o.x = f2bf(v.x); o.y = f2bf(v.y); o.z = f2bf(v.z); o.w = f2bf(v.w);
        *(ushort4*)(w3bf + idx) = o;
        return;
    }
    idx -= n3;
    if (idx < n4) {
        int i = idx / (64 * DI);
        int rem = idx - i * 64 * DI;
        int n = rem / DI, k = rem % DI;   // k multiple of 4, same row for all 4
        ushort4 o;
        if (n < XROW) {
            float4 v = *(const float4*)(xp + (size_t)i * XROW * DI + (size_t)n * DI + k);
            o.x = f2bf(v.x); o.y = f2bf(v.y); o.z = f2bf(v.z); o.w = f2bf(v.w);
        } else {
            o.x = o.y = o.z = o.w = 0;
        }
        *(ushort4*)(xpbf + (size_t)i * 64 * DI + (size_t)n * DI + k) = o;
        return;
    }
    idx -= n4;
    if (idx < n5) {
        float4 v = *(const float4*)(w2 + idx);
        ushort4 o; o.x = f2bf(v.x); o.y = f2bf(v.y); o.z = f2bf(v.z); o.w = f2bf(v.w);
        *(ushort4*)(w2bf + idx) = o;
    }
}

// ---------------------------------------------------------------- KNN (radix-select) + patch-embed MLP fused: one block per (b,p)
__global__ __launch_bounds__(256) void k_patch(
    const float* __restrict__ data,
    const float* __restrict__ w1, const float* __restrict__ b1,
    const float* __restrict__ g1, const float* __restrict__ be1,
    const unsigned short* __restrict__ w2bf, const float* __restrict__ b2,
    const float* __restrict__ g2, const float* __restrict__ be2,
    const unsigned short* __restrict__ w3bf, const float* __restrict__ b3,
    const float* __restrict__ g3, const float* __restrict__ be3,
    float* __restrict__ tokens, float* __restrict__ centers)
{
    const int bp = blockIdx.x;
    const int b = bp >> 6, p = bp & 63;
    const int tid = threadIdx.x;
    const float* X = data + (size_t)b * NN * 3;
    const float inv_den = 0.99999500003749968752f; // 1/sqrt(1+1e-5)

    __shared__ int hist[4][4][256];   // [round][wave][bin] -> zeroed once
    __shared__ int klist[KK];
    __shared__ int eqlist[256];
    __shared__ int s_kth, s_byte, s_cnt, s_eqcnt;
    __shared__ float nxs[KK * 3];
    __shared__ short h1b[KK][72];
    __shared__ short h2b[KK][136];

    const float cx = X[p * 32 * 3 + 0];
    const float cy = X[p * 32 * 3 + 1];
    const float cz = X[p * 32 * 3 + 2];
    if (tid == 0) {
        centers[(b * PP + p) * 3 + 0] = cx;
        centers[(b * PP + p) * 3 + 1] = cy;
        centers[(b * PP + p) * 3 + 2] = cz;
        s_kth = KK; s_cnt = 0; s_eqcnt = 0;
    }
    for (int i = tid; i < 4 * 4 * 256; i += 256) ((int*)hist)[i] = 0;

    const int wave = tid >> 6, lane = tid & 63;

    // ---- KNN phase: radix-select the 32 smallest d2 keys (set only; order irrelevant
    // because the patch MLP ends in max over K; ties -> smallest index, matching top_k)
    {
        unsigned key[8];
#pragma unroll
        for (int q = 0; q < 8; q++) {
            int i = tid + 256 * q;
            float dx = cx - X[i * 3 + 0];
            float dy = cy - X[i * 3 + 1];
            float dz = cz - X[i * 3 + 2];
            float d2 = dx * dx + dy * dy + dz * dz;
            key[q] = __float_as_uint(d2);   // non-negative float: uint order == float order
        }
        __syncthreads();   // hist zero + scalars visible
        unsigned prefix = 0;
        for (int rnd = 3; rnd >= 0; rnd--) {
            const int sh = rnd * 8;
            const int rslot = 3 - rnd;
            const unsigned pmask = (rnd == 3) ? 0u : (0xFFFFFFFFu << (8 * (rnd + 1)));
#pragma unroll
            for (int q = 0; q < 8; q++)
                if ((key[q] & pmask) == prefix)
                    atomicAdd(&hist[rslot][wave][(key[q] >> sh) & 255], 1);
            __syncthreads();
            if (wave == 0) {
                int c[4], tot = 0;
#pragma unroll
                for (int j = 0; j < 4; j++) {
                    int s4 = 0;
#pragma unroll
                    for (int w = 0; w < 4; w++) s4 += hist[rslot][w][lane * 4 + j];
                    c[j] = s4; tot += s4;
                }
                int inc = tot;
#pragma unroll
                for (int off = 1; off < 64; off <<= 1) {
                    int u = __shfl_up(inc, off);
                    if (lane >= off) inc += u;
                }
                int exc = inc - tot;
                int kth = s_kth;
                bool has = (exc < kth) && (exc + tot >= kth);
                unsigned long long bal = __ballot(has);
                int src = __ffsll(bal) - 1;
                if (lane == src) {
                    int rem = kth - exc;
                    int j = 0, cum = 0;
                    while (cum + c[j] < rem) { cum += c[j]; j++; }
                    s_byte = lane * 4 + j;
                    s_kth = rem - cum;
                }
            }
            __syncthreads();
            prefix |= ((unsigned)s_byte) << sh;
        }
        const unsigned kstar = prefix;
        const int need = s_kth;         // # to take from keys == kstar (>=1)
#pragma unroll
        for (int q = 0; q < 8; q++) {
            int i = tid + 256 * q;
            if (key[q] < kstar) {
                int pos = atomicAdd(&s_cnt, 1);
                klist[pos] = i;
            } else if (key[q] == kstar) {
                int pos = atomicAdd(&s_eqcnt, 1);
                if (pos < 256) eqlist[pos] = i;
            }
        }
        __syncthreads();
        if (tid == 0) {
            int base = s_cnt;           // == 32 - need
            int ne = s_eqcnt < 256 ? s_eqcnt : 256;
            for (int k = 0; k < need; k++) {
                int best = 0x7fffffff, bi = 0;
                for (int j = 0; j < ne; j++)
                    if (eqlist[j] < best) { best = eqlist[j]; bi = j; }
                klist[base + k] = best;
                eqlist[bi] = 0x7fffffff;
            }
        }
        __syncthreads();
    }

    // ---- patch-embed MLP phase
    if (tid < KK) {
        int q = klist[tid];
        nxs[tid * 3 + 0] = X[q * 3 + 0] - cx;
        nxs[tid * 3 + 1] = X[q * 3 + 1] - cy;
        nxs[tid * 3 + 2] = X[q * 3 + 2] - cz;
    }
    __syncthreads();

    // layer 1: 3 -> 64, fp32, output bf16 in LDS
    for (int e = tid; e < KK * 64; e += 256) {
        int j = e >> 6, c = e & 63;
        float v = nxs[j * 3 + 0] * w1[c * 3 + 0] + nxs[j * 3 + 1] * w1[c * 3 + 1] +
                  nxs[j * 3 + 2] * w1[c * 3 + 2] + b1[c];
        v = v * (g1[c] * inv_den) + be1[c];
        h1b[j][c] = (short)f2bf(gelu_exact(v));
    }
    __syncthreads();

    const int quad = lane >> 4, r = lane & 15;

    // layer 2: 64 -> 128 via MFMA (M=32, N=128, K=64); wave covers 32 cols
    {
        floatx4 acc2[2][2] = {};
#pragma unroll
        for (int ks = 0; ks < 2; ks++) {
            const int k0 = ks * 32;
            bf16x8 af[2], bfv[2];
#pragma unroll
            for (int mi = 0; mi < 2; mi++)
                af[mi] = *(const bf16x8*)&h1b[mi * 16 + r][quad * 8 + k0];
#pragma unroll
            for (int jj = 0; jj < 2; jj++) {
                int n = wave * 32 + jj * 16 + r;
                bfv[jj] = *(const bf16x8*)(w2bf + (size_t)n * 64 + quad * 8 + k0);
            }
#pragma unroll
            for (int mi = 0; mi < 2; mi++)
#pragma unroll
                for (int jj = 0; jj < 2; jj++)
                    acc2[mi][jj] = __builtin_amdgcn_mfma_f32_16x16x32_bf16(af[mi], bfv[jj], acc2[mi][jj], 0, 0, 0);
        }
#pragma unroll
        for (int jj = 0; jj < 2; jj++) {
            int col = wave * 32 + jj * 16 + r;
            float sc = g2[col] * inv_den;
            float bb = b2[col] * sc + be2[col];
#pragma unroll
            for (int mi = 0; mi < 2; mi++)
#pragma unroll
                for (int r2 = 0; r2 < 4; r2++) {
                    int row = mi * 16 + quad * 4 + r2;
                    h2b[row][col] = (short)f2bf(gelu_exact(acc2[mi][jj][r2] * sc + bb));
                }
        }
    }
    __syncthreads();

    // layer 3: 128 -> 384 via MFMA + max over K
    floatx4 acc3[2][6] = {};
#pragma unroll
    for (int ks = 0; ks < 4; ks++) {
        const int k0 = ks * 32;
        bf16x8 af[2];
        af[0] = *(const bf16x8*)&h2b[r][quad * 8 + k0];
        af[1] = *(const bf16x8*)&h2b[16 + r][quad * 8 + k0];
        bf16x8 bfv[6];
#pragma unroll
        for (int nj = 0; nj < 6; nj++) {
            int n = wave * 96 + nj * 16 + r;
            bfv[nj] = *(const bf16x8*)(w3bf + (size_t)n * 128 + quad * 8 + k0);
        }
#pragma unroll
        for (int mi = 0; mi < 2; mi++)
#pragma unroll
            for (int nj = 0; nj < 6; nj++)
                acc3[mi][nj] = __builtin_amdgcn_mfma_f32_16x16x32_bf16(af[mi], bfv[nj], acc3[mi][nj], 0, 0, 0);
    }
#pragma unroll
    for (int nj = 0; nj < 6; nj++) {
        int col = wave * 96 + nj * 16 + r;
        float sc = g3[col] * inv_den;
        float offc = b3[col] * sc + be3[col];
        float m = -3.4e38f;
#pragma unroll
        for (int mi = 0; mi < 2; mi++)
#pragma unroll
            for (int r2 = 0; r2 < 4; r2++)
                m = fmaxf(m, acc3[mi][nj][r2] * sc + offc);
        m = fmaxf(m, __shfl_xor(m, 16));
        m = fmaxf(m, __shfl_xor(m, 32));
        if (quad == 0) tokens[(size_t)bp * DD + col] = m;
    }
}

// ---------------------------------------------------------------- SFC orders + build token sequence fused.
__global__ __launch_bounds__(256) void k_sfc_build(
    const float* __restrict__ centers, const float* __restrict__ tokens,
    const float* __restrict__ hs, const float* __restrict__ hb,
    const float* __restrict__ ts2, const float* __restrict__ tb2,
    const float* __restrict__ pos, float* __restrict__ tout)
{
    const int b = blockIdx.y, part = blockIdx.x;
    const int tid = threadIdx.x;

    __shared__ float csh[PP][3];
    __shared__ float slo[3], shi[3];
    __shared__ unsigned khs[PP], kts[PP];
    __shared__ int oh[PP], ot[PP];

    if (tid < PP) {
        csh[tid][0] = centers[(b * PP + tid) * 3 + 0];
        csh[tid][1] = centers[(b * PP + tid) * 3 + 1];
        csh[tid][2] = centers[(b * PP + tid) * 3 + 2];
    }
    __syncthreads();
    if (tid == 0) {
        for (int k = 0; k < 3; k++) {
            float lo = csh[0][k], hi = csh[0][k];
            for (int j = 1; j < PP; j++) { lo = fminf(lo, csh[j][k]); hi = fmaxf(hi, csh[j][k]); }
            slo[k] = lo; shi[k] = hi;
        }
    }
    __syncthreads();
    if (tid < PP) {
        int q[3];
        for (int k = 0; k < 3; k++) {
            float t = (csh[tid][k] - slo[k]) / (shi[k] - slo[k] + 1e-6f) * 1023.0f;
            int qi = (int)t;
            qi = qi < 0 ? 0 : (qi > 1023 ? 1023 : qi);
            q[k] = qi;
        }
        khs[tid] = spread_bits((unsigned)q[0]) | (spread_bits((unsigned)q[1]) << 1) |
                   (spread_bits((unsigned)q[2]) << 2);
        kts[tid] = spread_bits((unsigned)q[2]) | (spread_bits((unsigned)q[1]) << 1) |
                   (spread_bits((unsigned)q[0]) << 2);
    }
    __syncthreads();
    if (tid < PP) {
        unsigned kh = khs[tid], kt = kts[tid];
        int rh = 0, rt = 0;
        for (int j = 0; j < PP; j++) {
            unsigned a = khs[j];
            rh += (a < kh) || (a == kh && j < tid);
            unsigned c = kts[j];
            rt += (c < kt) || (c == kt && j < tid);
        }
        oh[rh] = tid;
        ot[rt] = tid;
    }
    __syncthreads();

    const int base = part * (LL * DD / 24);  // 2048-element slice
    for (int e = tid; e < LL * DD / 24; e += 256) {
        int idx = base + e;
        int d = idx % DD;
        int l = idx / DD;
        float v;
        if (l < PP) {
            int src = oh[l];
            v = tokens[((size_t)b * PP + src) * DD + d] * hs[d] + hb[d] + pos[l * DD + d];
        } else {
            int l2 = l - PP;
            int src = ot[l2];
            v = tokens[((size_t)b * PP + src) * DD + d] * ts2[d] + tb2[d] + pos[l2 * DD + d];
        }
        tout[(size_t)b * LL * DD + idx] = v;
    }
}

// ---------------------------------------------------------------- LN: t -> tbf (bf16), one wave per row; also zero xdbl
__global__ __launch_bounds__(256) void k_stats(const float* __restrict__ t,
                                               const float* __restrict__ g,
                                               const float* __restrict__ gb,
                                               unsigned short* __restrict__ tbf,
                                               float* __restrict__ xdbl)
{
    const int tid = threadIdx.x;
    {
        int gi = blockIdx.x * 256 + tid;
        if (gi < NR * XROW) xdbl[gi] = 0.f;
    }
    const int wid = tid >> 6, lane = tid & 63;
    const int row = blockIdx.x * 4 + wid;
    const size_t base = (size_t)row * DD;
    float v[6];
    float s = 0.f, q = 0.f;
#pragma unroll
    for (int j = 0; j < 6; j++) {
        v[j] = t[base + lane + 64 * j];
        s += v[j]; q += v[j] * v[j];
    }
#pragma unroll
    for (int off = 32; off; off >>= 1) { s += __shfl_xor(s, off); q += __shfl_xor(q, off); }
    float mean = s * (1.0f / DD);
    float var = q * (1.0f / DD) - mean * mean;
    float inv = 1.0f / sqrtf(var + 1e-5f);
#pragma unroll
    for (int j = 0; j < 6; j++) {
        int i = lane + 64 * j;
        tbf[base + i] = f2bf((v[j] - mean) * inv * g[i] + gb[i]);
    }
}

// ---------------------------------------------------------------- xz MFMA GEMM (128 tokens x 64 cols) + fused conv/SiLU
// + fused xdbl split-K partial via atomicAdd.  grid (24, 8): x = 64-col tile (12 xc + 12 z), y = batch.
__global__ __launch_bounds__(256) void k_mfma_xz(
    const unsigned short* __restrict__ tbf,
    const unsigned short* __restrict__ inwbf,
    const float* __restrict__ cw, const float* __restrict__ cb,
    const unsigned short* __restrict__ xpbf,
    unsigned short* __restrict__ xcbf, unsigned short* __restrict__ zsbf,
    float* __restrict__ xdbl)
{
    __shared__ short ct[128][72];   // 64 cols + 8 pad
    const int tid = threadIdx.x;
    const int wave = tid >> 6, lane = tid & 63;
    const int quad = lane >> 4, r = lane & 15;
    const int wm = wave >> 1, wn = wave & 1;
    const int b = blockIdx.y;
    const int n0 = blockIdx.x * 64;
    const int m0 = b * 128 + wm * 64;

    floatx4 acc[4][2] = {};
    const unsigned short* Ab = tbf + (size_t)(m0 + r) * DD + quad * 8;
    const unsigned short* Bb = inwbf + (size_t)(n0 + wn * 32 + r) * DD + quad * 8;
    for (int k0 = 0; k0 < DD; k0 += 32) {
        bf16x8 af[4], bfv[2];
#pragma unroll
        for (int i = 0; i < 4; i++)
            af[i] = *(const bf16x8*)(Ab + (size_t)(i * 16) * DD + k0);
#pragma unroll
        for (int j = 0; j < 2; j++)
            bfv[j] = *(const bf16x8*)(Bb + (size_t)(j * 16) * DD + k0);
#pragma unroll
        for (int i = 0; i < 4; i++)
#pragma unroll
            for (int j = 0; j < 2; j++)
                acc[i][j] = __builtin_amdgcn_mfma_f32_16x16x32_bf16(af[i], bfv[j], acc[i][j], 0, 0, 0);
    }

    // C -> LDS (bf16).  row = wm*64 + i*16 + quad*4 + r2, col = wn*32 + j*16 + r
#pragma unroll
    for (int i = 0; i < 4; i++)
#pragma unroll
        for (int r2 = 0; r2 < 4; r2++) {
            short* cp = &ct[wm * 64 + i * 16 + quad * 4 + r2][wn * 32 + r];
#pragma unroll
            for (int j = 0; j < 2; j++)
                cp[j * 16] = (short)f2bf(acc[i][j][r2]);
        }
    __syncthreads();

    const int l0 = (tid >> 3) * 4;      // 4 rows per thread
    const int c0 = (tid & 7) * 8;       // 8 cols per thread
    if (n0 < DI) {
        float cwv[8][4], cbv[8];
#pragma unroll
        for (int q = 0; q < 8; q++) {
            *(float4*)cwv[q] = *(const float4*)(cw + (size_t)(n0 + c0 + q) * 4);
            cbv[q] = cb[n0 + c0 + q];
        }
        unsigned short ov[4][8];
#pragma unroll
        for (int dl = 0; dl < 4; dl++) {
            const int l = l0 + dl;
            float u[8];
#pragma unroll
            for (int q = 0; q < 8; q++) u[q] = cbv[q];
#pragma unroll
            for (int j = 0; j < DCONV; j++) {
                int lt = l - (DCONV - 1) + j;
                if (lt >= 0) {
                    bf16x8 x = *(const bf16x8*)&ct[lt][c0];
#pragma unroll
                    for (int q = 0; q < 8; q++) u[q] += bf2f(x[q]) * cwv[q][j];
                }
            }
#pragma unroll
            for (int q = 0; q < 8; q++) ov[dl][q] = f2bf(siluf(u[q]));
        }
        __syncthreads();   // all pre-conv reads done
#pragma unroll
        for (int dl = 0; dl < 4; dl++) {
            const int l = l0 + dl;
            *(bf16x8*)&ct[l][c0] = *(bf16x8*)ov[dl];
            *(bf16x8*)(xcbf + (size_t)(b * LL + l) * DI + n0 + c0) = *(bf16x8*)ov[dl];
        }
        __syncthreads();

        // fused xdbl partial: K = 64 (this block's channel slice), 4 waves x 32 rows
        floatx4 acc2[2][4] = {};
#pragma unroll
        for (int k0 = 0; k0 < 64; k0 += 32) {
            bf16x8 af2[2], bfv2[4];
#pragma unroll
            for (int i = 0; i < 2; i++)
                af2[i] = *(const bf16x8*)&ct[wave * 32 + i * 16 + r][k0 + quad * 8];
#pragma unroll
            for (int nj = 0; nj < 4; nj++)
                bfv2[nj] = *(const bf16x8*)(xpbf + (size_t)(nj * 16 + r) * DI + n0 + k0 + quad * 8);
#pragma unroll
            for (int i = 0; i < 2; i++)
#pragma unroll
                for (int nj = 0; nj < 4; nj++)
                    acc2[i][nj] = __builtin_amdgcn_mfma_f32_16x16x32_bf16(af2[i], bfv2[nj], acc2[i][nj], 0, 0, 0);
        }
#pragma unroll
        for (int i = 0; i < 2; i++)
#pragma unroll
            for (int nj = 0; nj < 4; nj++) {
                int col = nj * 16 + r;
                if (col < XROW) {
#pragma unroll
                    for (int r2 = 0; r2 < 4; r2++) {
                        int row = b * LL + wave * 32 + i * 16 + quad * 4 + r2;
                        unsafeAtomicAdd(&xdbl[(size_t)row * XROW + col], acc2[i][nj][r2]);
                    }
                }
            }
    } else {
        const int nz = n0 - DI;
#pragma unroll
        for (int dl = 0; dl < 4; dl++) {
            const int l = l0 + dl;
            bf16x8 x = *(const bf16x8*)&ct[l][c0];
            unsigned short o[8];
#pragma unroll
            for (int q = 0; q < 8; q++) o[q] = f2bf(siluf(bf2f(x[q])));
            *(bf16x8*)(zsbf + (size_t)(b * LL + l) * DI + nz + c0) = *(bf16x8*)o;
        }
    }
}

// ---------------------------------------------------------------- chunk-parallel selective scan (1 channel / 128-thr block)
__global__ __launch_bounds__(128) void k_scan(
    const float* __restrict__ xdbl,
    const unsigned short* __restrict__ xcbf, const unsigned short* __restrict__ zsbf,
    const float* __restrict__ dtw, const float* __restrict__ dtb,
    const float* __restrict__ Alog, const float* __restrict__ Dp,
    unsigned short* __restrict__ ybf)
{
    const int tid = threadIdx.x;
    const int b = blockIdx.x / DI;
    const int d = blockIdx.x % DI;

    __shared__ float sdel[LL];
    __shared__ float sdus[LL];
    __shared__ float sus[LL];
    __shared__ float szs[LL];
    __shared__ float negA[DS];
    __shared__ float ApL[DS][9];
    __shared__ float HlL[DS][9];
    __shared__ float hst[DS][9];

    // phase 1: per-token scalars (t = tid)
    {
        const int t = tid;
        const size_t row = (size_t)b * LL + t;
        const float* xd = xdbl + row * XROW;
        const float* w = dtw + d * DTR;
        float acc = dtb[d];
#pragma unroll
        for (int k = 0; k < DTR; k += 4) {
            float4 xv = *(const float4*)(xd + k);
            float4 wv = *(const float4*)(w + k);
            acc += xv.x * wv.x + xv.y * wv.y + xv.z * wv.z + xv.w * wv.w;
        }
        float delta = fmaxf(acc, 0.f) + log1pf(__expf(-fabsf(acc)));  // softplus
        float u = bf2f((short)xcbf[row * DI + d]);
        sdel[t] = delta;
        sdus[t] = delta * u;
        sus[t] = u;
        szs[t] = bf2f((short)zsbf[row * DI + d]);
    }
    if (tid < DS) negA[tid] = -__expf(Alog[d * DS + tid]);
    __syncthreads();

    const int s = tid & 15;
    const int c = tid >> 4;           // chunk 0..7
    const float* xB = xdbl + ((size_t)b * LL + c * 16) * XROW + DTR + s;

    float a_r[16], duB_r[16], C_r[16];
    {
        float h = 0.f, Ap = 1.f;
        const float na = negA[s];
#pragma unroll
        for (int q = 0; q < 16; q++) {
            int t = c * 16 + q;
            float a = __expf(sdel[t] * na);
            float Bv = xB[(size_t)q * XROW];
            float Cv = xB[(size_t)q * XROW + DS];
            a_r[q] = a;
            duB_r[q] = sdus[t] * Bv;
            C_r[q] = Cv;
            h = h * a + duB_r[q];
            Ap *= a;
        }
        ApL[s][c] = Ap;
        HlL[s][c] = h;
    }
    __syncthreads();
    if (tid < DS) {
        float hs = 0.f;
#pragma unroll
        for (int cc = 0; cc < 8; cc++) {
            hst[tid][cc] = hs;
            hs = ApL[tid][cc] * hs + HlL[tid][cc];
        }
    }
    __syncthreads();

    {
        const float Dd = Dp[d];
        float h = hst[s][c];
        unsigned short* yc = ybf + ((size_t)b * LL + c * 16) * DI + d;
#pragma unroll
        for (int q = 0; q < 16; q++) {
            h = h * a_r[q] + duB_r[q];
            float p = h * C_r[q];
            p += __shfl_xor(p, 1, 16);
            p += __shfl_xor(p, 2, 16);
            p += __shfl_xor(p, 4, 16);
            p += __shfl_xor(p, 8, 16);
            if (s == 0) {
                int t = c * 16 + q;
                yc[(size_t)q * DI] = f2bf((p + Dd * sus[t]) * szs[t]);
            }
        }
    }
}

// ---------------------------------------------------------------- out-proj MFMA GEMM, split-K=2, atomic residual RMW on t.
// grid (6, 32, 2): x = 64-col tile, y = 32-row tile, z = K-half (384 each).
__global__ __launch_bounds__(256) void k_mfma_op(
    const unsigned short* __restrict__ ybf,
    const unsigned short* __restrict__ owbf,
    float* __restrict__ t)
{
    const int tid = threadIdx.x;
    const int wave = tid >> 6, lane = tid & 63;
    const int quad = lane >> 4, r = lane & 15;
    const int wr2 = wave >> 1, wc = wave & 1;
    const int n0 = blockIdx.x * 64 + wc * 32;
    const int m0 = blockIdx.y * 32 + wr2 * 16;
    const int kb = blockIdx.z * (DI / 2);

    floatx4 acc[2] = {};
    const unsigned short* Ab = ybf + (size_t)(m0 + r) * DI + kb + quad * 8;
    const unsigned short* Bb = owbf + (size_t)(n0 + r) * DI + kb + quad * 8;
    for (int k0 = 0; k0 < DI / 2; k0 += 32) {
        bf16x8 af = *(const bf16x8*)(Ab + k0);
        bf16x8 b0 = *(const bf16x8*)(Bb + k0);
        bf16x8 b1 = *(const bf16x8*)(Bb + (size_t)16 * DI + k0);
        acc[0] = __builtin_amdgcn_mfma_f32_16x16x32_bf16(af, b0, acc[0], 0, 0, 0);
        acc[1] = __builtin_amdgcn_mfma_f32_16x16x32_bf16(af, b1, acc[1], 0, 0, 0);
    }

#pragma unroll
    for (int j = 0; j < 2; j++) {
        int col = n0 + j * 16 + r;
#pragma unroll
        for (int r2 = 0; r2 < 4; r2++) {
            int row = m0 + quad * 4 + r2;
            unsafeAtomicAdd(t + (size_t)row * DD + col, acc[j][r2]);
        }
    }
}

// ---------------------------------------------------------------- final LN + partial mean-pool: grid (8 chunks, 8 batches)
__global__ __launch_bounds__(256) void k_lnpool(const float* __restrict__ t,
                                                const float* __restrict__ ng,
                                                const float* __restrict__ nb,
                                                float* __restrict__ pparts)  // [BB][8][DD]
{
    const int b = blockIdx.y, chunk = blockIdx.x;
    const int tid = threadIdx.x;
    const int wave = tid >> 6, lane = tid & 63;
    __shared__ float pw[4][DD];

    for (int c = lane; c < DD; c += 64) pw[wave][c] = 0.f;
    __syncthreads();

    for (int rr = 0; rr < 4; rr++) {
        const int row = b * LL + chunk * 16 + wave * 4 + rr;
        const float* xr = t + (size_t)row * DD;
        float v[6];
        float s = 0.f, q = 0.f;
#pragma unroll
        for (int j = 0; j < 6; j++) { v[j] = xr[lane + 64 * j]; s += v[j]; q += v[j] * v[j]; }
#pragma unroll
        for (int off = 32; off; off >>= 1) { s += __shfl_xor(s, off); q += __shfl_xor(q, off); }
        float mean = s * (1.0f / DD);
        float var = q * (1.0f / DD) - mean * mean;
        float inv = 1.0f / sqrtf(var + 1e-5f);
#pragma unroll
        for (int j = 0; j < 6; j++) {
            int c = lane + 64 * j;
            pw[wave][c] += (v[j] - mean) * inv * ng[c] + nb[c];
        }
    }
    __syncthreads();
    float* out = pparts + ((size_t)b * 8 + chunk) * DD;
    for (int c = tid; c < DD; c += 256)
        out[c] = pw[0][c] + pw[1][c] + pw[2][c] + pw[3][c];
}

// ---------------------------------------------------------------- head MLP from pooled partials, one block per batch
__global__ __launch_bounds__(256) void k_mlp(const float* __restrict__ pparts,
    const float* __restrict__ w1, const float* __restrict__ b1,
    const float* __restrict__ w2, const float* __restrict__ b2,
    const float* __restrict__ w3, const float* __restrict__ b3,
    float* __restrict__ out)
{
    const int b = blockIdx.x, tid = threadIdx.x;
    __shared__ float pl[DD];
    __shared__ float h1[256];
    __shared__ float h2[64];
    for (int c = tid; c < DD; c += 256) {
        const float* pp = pparts + (size_t)b * 8 * DD + c;
        float s = 0.f;
#pragma unroll
        for (int z = 0; z < 8; z++) s += pp[z * DD];
        pl[c] = s * (1.0f / LL);
    }
    __syncthreads();

    {
        float acc = b1[tid];
        const float* wr = w1 + (size_t)tid * DD;
        for (int k = 0; k < DD; k++) acc += pl[k] * wr[k];
        h1[tid] = fmaxf(acc, 0.f);
    }
    __syncthreads();
    if (tid < 64) {
        float acc = b2[tid];
        const float* wr = w2 + (size_t)tid * 256;
        for (int k = 0; k < 256; k++) acc += h1[k] * wr[k];
        h2[tid] = fmaxf(acc, 0.f);
    }
    __syncthreads();
    if (tid < NC) {
        float acc = b3[tid];
        const float* wr = w3 + (size_t)tid * 64;
        for (int k = 0; k < 64; k++) acc += h2[k] * wr[k];
        out[b * NC + tid] = acc;
    }
}

// ---------------------------------------------------------------- launch
extern "C" void kernel_launch(void* const* d_in, const int* in_sizes, int n_in,
                              void* d_out, int out_size, void* d_ws, size_t ws_size,
                              hipStream_t stream)
{
    const float* data      = (const float*)d_in[0];
    const float* pe_w1     = (const float*)d_in[1];
    const float* pe_b1     = (const float*)d_in[2];
    const float* pe_g1     = (const float*)d_in[3];
    const float* pe_be1    = (const float*)d_in[4];
    const float* pe_w2     = (const float*)d_in[5];
    const float* pe_b2     = (const float*)d_in[6];
    const float* pe_g2     = (const float*)d_in[7];
    const float* pe_be2    = (const float*)d_in[8];
    const float* pe_w3     = (const float*)d_in[9];
    const float* pe_b3     = (const float*)d_in[10];
    const float* pe_g3     = (const float*)d_in[11];
    const float* pe_be3    = (const float*)d_in[12];
    const float* oi_h_scale  = (const float*)d_in[13];
    const float* oi_h_shift  = (const float*)d_in[14];
    const float* oi_th_scale = (const float*)d_in[15];
    const float* oi_th_shift = (const float*)d_in[16];
    const float* pos_embed = (const float*)d_in[17];
    const float* blk_ln_g  = (const float*)d_in[18];
    const float* blk_ln_b  = (const float*)d_in[19];
    const float* blk_in_w  = (const float*)d_in[20];
    const float* blk_conv_w = (const float*)d_in[21];
    const float* blk_conv_b = (const float*)d_in[22];
    const float* blk_xp_w  = (const float*)d_in[23];
    const float* blk_dt_w  = (const float*)d_in[24];
    const float* blk_dt_b  = (const float*)d_in[25];
    const float* blk_Alog  = (const float*)d_in[26];
    const float* blk_D     = (const float*)d_in[27];
    const float* blk_out_w = (const float*)d_in[28];
    const float* norm_g    = (const float*)d_in[29];
    const float* norm_b    = (const float*)d_in[30];
    const float* mlp_w1    = (const float*)d_in[31];
    const float* mlp_b1    = (const float*)d_in[32];
    const float* mlp_w2    = (const float*)d_in[33];
    const float* mlp_b2    = (const float*)d_in[34];
    const float* mlp_w3    = (const float*)d_in[35];
    const float* mlp_b3    = (const float*)d_in[36];

    float* ws = (float*)d_ws;
    size_t off = 0;
    auto alloc = [&](size_t n) { float* p = ws + off; off += (n + 63) & ~(size_t)63; return p; };
    float* tokens  = alloc((size_t)BB * PP * DD);
    float* centers = alloc((size_t)BB * PP * 3);
    float* t    = alloc((size_t)NR * DD);
    float* xdbl = alloc((size_t)NR * XROW);
    float* pparts  = alloc((size_t)BB * 8 * DD);
    unsigned short* tbf   = (unsigned short*)alloc((size_t)NR * DD / 2);
    unsigned short* xcbf  = (unsigned short*)alloc((size_t)NR * DI / 2);
    unsigned short* zsbf  = (unsigned short*)alloc((size_t)NR * DI / 2);
    unsigned short* ybf   = (unsigned short*)alloc((size_t)NR * DI / 2);
    unsigned short* inwbf = (unsigned short*)alloc((size_t)DEPTH * 2 * DI * DD / 2);
    unsigned short* owbf  = (unsigned short*)alloc((size_t)DEPTH * DD * DI / 2);
    unsigned short* xpbf  = (unsigned short*)alloc((size_t)DEPTH * 64 * DI / 2);
    unsigned short* w3bf  = (unsigned short*)alloc((size_t)DD * 128 / 2);
    unsigned short* w2bf  = (unsigned short*)alloc((size_t)128 * 64 / 2);

    // one-shot weight conversion (all five targets, 4 elems/thread)
    {
        const int total = DEPTH * 2 * DI * DD + DEPTH * DD * DI + DD * 128 + DEPTH * 64 * DI + 128 * 64;
        k_cvt<<<(total / 4 + 255) / 256, 256, 0, stream>>>(
            blk_in_w, blk_out_w, pe_w3, blk_xp_w, pe_w2, inwbf, owbf, w3bf, xpbf, w2bf);
    }

    k_patch<<<BB * PP, 256, 0, stream>>>(data,
        pe_w1, pe_b1, pe_g1, pe_be1, w2bf, pe_b2, pe_g2, pe_be2,
        w3bf, pe_b3, pe_g3, pe_be3, tokens, centers);
    k_sfc_build<<<dim3(24, BB), 256, 0, stream>>>(centers, tokens,
        oi_h_scale, oi_h_shift, oi_th_scale, oi_th_shift, pos_embed, t);

    for (int i = 0; i < DEPTH; i++) {
        const float* ln_g = blk_ln_g + i * DD;
        const float* ln_b = blk_ln_b + i * DD;
        const float* cw   = blk_conv_w + (size_t)i * DI * DCONV;
        const float* cb   = blk_conv_b + (size_t)i * DI;
        const float* dtw  = blk_dt_w + (size_t)i * DI * DTR;
        const float* dtb  = blk_dt_b + (size_t)i * DI;
        const float* Al   = blk_Alog + (size_t)i * DI * DS;
        const float* Dpp  = blk_D + (size_t)i * DI;
        const unsigned short* inw = inwbf + (size_t)i * 2 * DI * DD;
        const unsigned short* ow  = owbf + (size_t)i * DD * DI;
        const unsigned short* xpb = xpbf + (size_t)i * 64 * DI;

        k_stats<<<NR / 4, 256, 0, stream>>>(t, ln_g, ln_b, tbf, xdbl);
        k_mfma_xz<<<dim3(24, BB), 256, 0, stream>>>(
            tbf, inw, cw, cb, xpb, xcbf, zsbf, xdbl);
        k_scan<<<BB * DI, 128, 0, stream>>>(xdbl, xcbf, zsbf, dtw, dtb, Al, Dpp, ybf);
        k_mfma_op<<<dim3(DD / 64, NR / 32, 2), 256, 0, stream>>>(ybf, ow, t);
    }

    k_lnpool<<<dim3(8, BB), 256, 0, stream>>>(t, norm_g, norm_b, pparts);
    k_mlp<<<BB, 256, 0, stream>>>(pparts, mlp_w1, mlp_b1, mlp_w2, mlp_b2, mlp_w3, mlp_b3,
                                  (float*)d_out);
}